// Round 12
// baseline (104.925 us; speedup 1.0000x reference)
//
#include <hip/hip_runtime.h>
#include <hip/hip_bf16.h>

// ---------------------------------------------------------------------------
// ClusterGNN fused pipeline for MI355X (gfx950).  Round 12.
//   - conv2: persistent grid (64,16)=1024 blocks (exactly 1 resident round @
//     4/CU), each looping 2-3 subtiles; B-frags/BN-coefs loaded once/block.
//   - k_bn3 deleted: k_order writes inverse index; k_final computes BN3
//     coefs in LDS and applies to hi[inv[cell]] directly.  8 dispatches.
// ---------------------------------------------------------------------------

typedef short bfrag8 __attribute__((ext_vector_type(8)));   // 8 bf16 (4 VGPR)
typedef float f32x4  __attribute__((ext_vector_type(4)));
typedef int   i32x4  __attribute__((ext_vector_type(4)));
typedef short s4v    __attribute__((ext_vector_type(4)));

#define DI __device__ __forceinline__

DI unsigned short f2bf(float f) {
  return __builtin_bit_cast(unsigned short, __float2bfloat16(f));
}
DI float bf2f(unsigned short u) {
  return __builtin_bit_cast(float, ((unsigned)u) << 16);
}
// pack two floats to two bf16 (round-half-up) in one u32 (lo -> low half)
DI unsigned pack2bf(float lo, float hi) {
  unsigned ulo = __builtin_bit_cast(unsigned, lo) + 0x8000u;
  unsigned uhi = __builtin_bit_cast(unsigned, hi) + 0x8000u;
  return __builtin_amdgcn_perm(uhi, ulo, 0x07060302u);
}
// scale all 8 bf16 lanes of a fragment by sc
DI bfrag8 scale_frag(bfrag8 v, float sc) {
  i32x4 wi = __builtin_bit_cast(i32x4, v);
  i32x4 o;
#pragma unroll
  for (int j = 0; j < 4; ++j) {
    unsigned u = (unsigned)wi[j];
    float lo = bf2f((unsigned short)(u & 0xffffu));
    float hi = bf2f((unsigned short)(u >> 16));
    o[j] = (int)pack2bf(lo * sc, hi * sc);
  }
  return __builtin_bit_cast(bfrag8, o);
}

// ------------------------ prep: pool + wcvt + stats zero --------------------
__global__ __launch_bounds__(256) void k_prep(
    const float* __restrict__ xc, float* __restrict__ x,
    const float* __restrict__ w1, const float* __restrict__ w2,
    unsigned short* __restrict__ w1b, unsigned short* __restrict__ w2p,
    float* __restrict__ statsz) {
  const int bid = blockIdx.x, tid = threadIdx.x;
  if (bid < 128) {
    int idx = bid * 256 + tid;      // 32768 float4s
    int c4 = idx & 7, g = idx >> 3;
    int gz = g & 15, gy = (g >> 4) & 15, gx = g >> 8;
    f32x4 s = {0.f, 0.f, 0.f, 0.f};
    for (int ix = 0; ix < 4; ++ix)
      for (int iy = 0; iy < 4; ++iy)
        for (int iz = 0; iz < 4; ++iz) {
          int X = gx * 4 + ix, Y = gy * 4 + iy, Z = gz * 4 + iz;
          s += *(const f32x4*)&xc[(size_t)(((X << 6) | Y) << 6 | Z) * 32 + c4 * 4];
        }
    *(f32x4*)&x[(size_t)idx * 4] = s * (1.f / 64.f);
    if (bid < 24) statsz[bid * 256 + tid] = 0.f;   // stats1|2|3 zero (6144)
  } else {
    int i = (bid - 128) * 256 + tid;               // 98304
    if (i < 32768) w1b[i] = f2bf(w1[i]);
    int o = i >> 6, cc = i & 63;
    int s = cc >> 5, kp = cc & 31;
    int src = 32 * s + 16 * ((kp >> 2) & 1) + 4 * (kp >> 3) + (kp & 3);
    w2p[i] = f2bf(w2[(size_t)o * 64 + src]);
  }
}

// ------------------- order + gather + centroid + inverse --------------------
__global__ __launch_bounds__(256) void k_order(
    const int* __restrict__ ci, const float* __restrict__ x,
    int* __restrict__ order, int* __restrict__ inv, float* __restrict__ xi,
    unsigned short* __restrict__ xib, float* __restrict__ centb) {
  const int k = blockIdx.x, t = threadIdx.x;
  __shared__ int scnt[256];
  __shared__ int ordl[256];
  __shared__ unsigned short xls[256 * 36];
  __shared__ float red[256];

  int match[16];
  int cnt = 0;
#pragma unroll
  for (int j = 0; j < 16; ++j) { match[j] = (ci[t * 16 + j] == k); cnt += match[j]; }
  scnt[t] = cnt;
  __syncthreads();
  for (int off = 1; off < 256; off <<= 1) {
    int v = (t >= off) ? scnt[t - off] : 0;
    __syncthreads();
    scnt[t] += v;
    __syncthreads();
  }
  int pos = scnt[t] - cnt;
#pragma unroll
  for (int j = 0; j < 16; ++j)
    if (match[j]) ordl[pos++] = t * 16 + j;
  __syncthreads();
  int src = ordl[t];
  order[k * 256 + t] = src;
  inv[src] = k * 256 + t;
  const f32x4* xr = (const f32x4*)(x + (size_t)src * 32);
  f32x4* xo = (f32x4*)(xi + ((size_t)k * 256 + t) * 32);
  uint2* xb = (uint2*)(xib + ((size_t)k * 256 + t) * 32);
  uint2* xl = (uint2*)&xls[t * 36];
#pragma unroll
  for (int c = 0; c < 8; ++c) {
    f32x4 v = xr[c];
    xo[c] = v;
    unsigned int lo = f2bf(v[0]) | ((unsigned)f2bf(v[1]) << 16);
    unsigned int hi = f2bf(v[2]) | ((unsigned)f2bf(v[3]) << 16);
    xb[c] = make_uint2(lo, hi);
    xl[c] = make_uint2(lo, hi);
  }
  __syncthreads();

  {  // centroid
    int c = t & 31, rp = t >> 5;
    float ssum = 0.f;
    for (int r = rp; r < 256; r += 8) ssum += bf2f(xls[r * 36 + c]);
    red[t] = ssum;
  }
  __syncthreads();
  if (t < 32) {
    float tot = 0.f;
#pragma unroll
    for (int g = 0; g < 8; ++g) tot += red[g * 32 + t];
    centb[k * 32 + t] = tot * (1.f / 256.f);
  }
}

// ------------------------------- MLP ----------------------------------------
__global__ __launch_bounds__(256) void k_mlp(
    const float* __restrict__ centb,
    const float* __restrict__ mw1, const float* __restrict__ mb1,
    const float* __restrict__ mw2, const float* __restrict__ mb2,
    const float* __restrict__ mw3, const float* __restrict__ mb3,
    float* __restrict__ swb) {
  const int k = blockIdx.y, bx = blockIdx.x, t = threadIdx.x;
  __shared__ float cent[32];
  __shared__ float h1[128];
  __shared__ float h2s[256];
  __shared__ float red[256];
  if (t < 32) cent[t] = centb[k * 32 + t];
  __syncthreads();
  if (t < 128) {
    float s = mb1[t];
#pragma unroll
    for (int c = 0; c < 32; ++c) s += cent[c] * mw1[c * 128 + t];
    h1[t] = fmaxf(s, 0.f);
  }
  __syncthreads();
  {
    float s = mb2[t];
    for (int j = 0; j < 128; ++j) s += h1[j] * mw2[j * 256 + t];
    h2s[t] = fmaxf(s, 0.f);
  }
  __syncthreads();
  const int o = bx * 64 + (t & 63);
  const int part = t >> 6;
  float s = 0.f;
  const float* m3 = mw3 + (size_t)(part * 64) * 1024 + o;
#pragma unroll 8
  for (int j = 0; j < 64; ++j) s += h2s[part * 64 + j] * m3[j * 1024];
  red[t] = s;
  __syncthreads();
  if (t < 64) {
    float tot = red[t] + red[t + 64] + red[t + 128] + red[t + 192] + mb3[o];
    swb[k * 1024 + o] = 1.f / (1.f + __expf(-tot));
  }
}

// ------------------- stats passes (modes 0/1, sampled 1/4) ------------------
template <int MODE>
__global__ __launch_bounds__(256, (MODE == 1) ? 3 : 4) void k_conv01(
    const float* __restrict__ xi,
    const unsigned short* __restrict__ w1b,
    const unsigned short* __restrict__ w2p,
    float* stats1, float* stats2,
    const float* __restrict__ bn1g, const float* __restrict__ bn1b) {
  const int k   = blockIdx.y;
  const int t36 = blockIdx.x;
  int a = 0, rem = t36;
  while (rem >= 8 - a) { rem -= 8 - a; ++a; }
  const int b = a + rem;                 // a<=b
  const float w = (a == b) ? 1.f : 2.f;

  const int tid = threadIdx.x;
  const int lane = tid & 63;
  const int wv  = tid >> 6;
  const int l15 = lane & 15;
  const int lg  = lane >> 4;
  const int Pb0 = a * 32, Qb = b * 32;

  constexpr int NF  = (MODE == 0) ? 4 : 6;
  constexpr int NCH = NF * 4;

  __shared__ __align__(16) float xp[32][32];
  __shared__ float sred[192];
  __shared__ __align__(16) float s1s[(MODE == 1) ? 64 : 1];
  __shared__ __align__(16) float t1s[(MODE == 1) ? 64 : 1];

  const float* xik = xi + (size_t)k * 8192;
  {
    int r = tid >> 3, c4 = (tid & 7) * 4;
    *(f32x4*)&xp[r][c4] = *(const f32x4*)(xik + (size_t)(Pb0 + r) * 32 + c4);
  }
  if (tid < 192) sred[tid] = 0.f;
  if constexpr (MODE == 1) {
    if (tid >= 192) {
      const int ch = tid - 192;
      float sum = stats1[k * 128 + 2 * ch], sqv = stats1[k * 128 + 2 * ch + 1];
      float mean = sum * (1.f / 16384.f);
      float var  = sqv * (1.f / 16384.f) - mean * mean;
      float s = bn1g[k * 64 + ch] * rsqrtf(fmaxf(var, 0.f) + 1e-5f);
      s1s[ch] = s;
      t1s[ch] = bn1b[k * 64 + ch] - mean * s;
    }
  }

  float qv[2][8];
#pragma unroll
  for (int qg = 0; qg < 2; ++qg) {
    const f32x4* src = (const f32x4*)(xik + (size_t)(Qb + qg * 16 + l15) * 32 + lg * 8);
    f32x4 v0 = src[0], v1 = src[1];
#pragma unroll
    for (int j = 0; j < 4; ++j) { qv[qg][j] = v0[j]; qv[qg][4 + j] = v1[j]; }
  }

  bfrag8 B1[4];
  {
    const unsigned short* w1k = w1b + k * 2048;
#pragma unroll
    for (int f = 0; f < 4; ++f)
      B1[f] = *(const bfrag8*)(w1k + (16 * f + l15) * 32 + lg * 8);
  }
  bfrag8 B2[6][2];
  if constexpr (MODE == 1) {
    const unsigned short* w2k = w2p + k * 6144;
#pragma unroll
    for (int f2 = 0; f2 < 6; ++f2) {
      B2[f2][0] = *(const bfrag8*)(w2k + (16 * f2 + l15) * 64 + lg * 8);
      B2[f2][1] = *(const bfrag8*)(w2k + (16 * f2 + l15) * 64 + 32 + lg * 8);
    }
  }

  float ss[24], sq[24];
#pragma unroll
  for (int i = 0; i < 24; ++i) { ss[i] = 0.f; sq[i] = 0.f; }

  __syncthreads();

  if constexpr (MODE == 1) {
#pragma unroll
    for (int f = 0; f < 4; ++f)
      B1[f] = scale_frag(B1[f], s1s[16 * f + l15]);
  }

  const f32x4 z = {0.f, 0.f, 0.f, 0.f};

  bfrag8 dfa[4];
#pragma unroll
  for (int rp = 0; rp < 4; ++rp) {
    const int pl = rp >> 1, qg = rp & 1;
    const int plocal = wv * 8 + pl * 4;
    const float* xpp = &xp[plocal][lg * 8];
    f32x4 p0 = *(const f32x4*)xpp;
    f32x4 p1 = *(const f32x4*)(xpp + 4);
    float pvv[8];
#pragma unroll
    for (int j = 0; j < 4; ++j) { pvv[j] = p0[j]; pvv[4 + j] = p1[j]; }
    unsigned dw[4];
#pragma unroll
    for (int wj = 0; wj < 4; ++wj) {
      float d0 = fabsf(qv[qg][2 * wj]     - pvv[2 * wj]);
      float d1 = fabsf(qv[qg][2 * wj + 1] - pvv[2 * wj + 1]);
      dw[wj] = pack2bf(d0, d1);
    }
    i32x4 dwi = {(int)dw[0], (int)dw[1], (int)dw[2], (int)dw[3]};
    dfa[rp] = __builtin_bit_cast(bfrag8, dwi);
  }

#pragma unroll
  for (int rp = 0; rp < 4; ++rp) {
    f32x4 acc1[4];
    __builtin_amdgcn_s_setprio(1);
#pragma unroll
    for (int f = 0; f < 4; ++f) {
      f32x4 cin;
      if constexpr (MODE == 0) cin = z;
      else cin = *(const f32x4*)&t1s[16 * f + 4 * lg];
      acc1[f] = __builtin_amdgcn_mfma_f32_16x16x32_bf16(B1[f], dfa[rp], cin, 0, 0, 0);
    }
    __builtin_amdgcn_s_setprio(0);

    if constexpr (MODE == 0) {
#pragma unroll
      for (int f = 0; f < 4; ++f)
#pragma unroll
        for (int r = 0; r < 4; ++r) {
          float h = acc1[f][r];
          ss[f * 4 + r] += h; sq[f * 4 + r] = fmaf(h, h, sq[f * 4 + r]);
        }
    } else {
      unsigned paw[8];
#pragma unroll
      for (int f = 0; f < 4; ++f) {
        float h0 = acc1[f][0], h1 = acc1[f][1], h2 = acc1[f][2], h3 = acc1[f][3];
        h0 = fmaxf(h0, 0.2f * h0); h1 = fmaxf(h1, 0.2f * h1);
        h2 = fmaxf(h2, 0.2f * h2); h3 = fmaxf(h3, 0.2f * h3);
        paw[f * 2]     = pack2bf(h0, h1);
        paw[f * 2 + 1] = pack2bf(h2, h3);
      }
      i32x4 pa0i = {(int)paw[0], (int)paw[1], (int)paw[2], (int)paw[3]};
      i32x4 pa1i = {(int)paw[4], (int)paw[5], (int)paw[6], (int)paw[7]};
      bfrag8 pa0 = __builtin_bit_cast(bfrag8, pa0i);
      bfrag8 pa1 = __builtin_bit_cast(bfrag8, pa1i);

      __builtin_amdgcn_s_setprio(1);
#pragma unroll
      for (int f2 = 0; f2 < 6; ++f2) {
        f32x4 acc = __builtin_amdgcn_mfma_f32_16x16x32_bf16(B2[f2][0], pa0, z, 0, 0, 0);
        acc = __builtin_amdgcn_mfma_f32_16x16x32_bf16(B2[f2][1], pa1, acc, 0, 0, 0);
#pragma unroll
        for (int r = 0; r < 4; ++r) {
          float h = acc[r];
          ss[f2 * 4 + r] += h; sq[f2 * 4 + r] = fmaf(h, h, sq[f2 * 4 + r]);
        }
      }
      __builtin_amdgcn_s_setprio(0);
    }
  }

#pragma unroll
  for (int i = 0; i < NCH; ++i) {
#pragma unroll
    for (int m = 1; m <= 8; m <<= 1) {
      ss[i] += __shfl_xor(ss[i], m);
      sq[i] += __shfl_xor(sq[i], m);
    }
  }
  if (l15 == 0) {
#pragma unroll
    for (int i = 0; i < NCH; ++i) {
      int ch = 16 * (i >> 2) + 4 * lg + (i & 3);
      atomicAdd(&sred[ch * 2 + 0], ss[i] * w);
      atomicAdd(&sred[ch * 2 + 1], sq[i] * w);
    }
  }
  __syncthreads();
  float* gs = (MODE == 0) ? stats1 : stats2;
  if (tid < 2 * 16 * NF) atomicAdd(&gs[k * (2 * 16 * NF) + tid], sred[tid]);
}

// ------------------- logits pass (persistent subtile loop) ------------------
__global__ __launch_bounds__(256, 4) void k_conv2(
    const float* __restrict__ xi,
    const unsigned short* __restrict__ w1b,
    const unsigned short* __restrict__ w2p,
    const float* __restrict__ stats1, const float* __restrict__ stats2,
    const float* __restrict__ bn1g, const float* __restrict__ bn1b,
    const float* __restrict__ bn2g, const float* __restrict__ bn2b,
    const float* __restrict__ c3w,
    float* __restrict__ logits) {
  const int k  = blockIdx.y;
  const int bx = blockIdx.x;             // 0..63
  const int tid = threadIdx.x;
  const int lane = tid & 63;
  const int wv  = tid >> 6;
  const int l15 = lane & 15;
  const int lg  = lane >> 4;

  __shared__ __align__(16) float xp[16][32];
  __shared__ __align__(16) float s1s[64];
  __shared__ __align__(16) float t1s[64];
  __shared__ __align__(16) float sw2s[96];
  __shared__ __align__(16) float cb2s[96];
  __shared__ __align__(16) float s42s[96];
  __shared__ float lt[16][17];

  const float* xik = xi + (size_t)k * 8192;

  // ---- once-per-block: BN coefficients ----
  if (tid < 64) {
    const int ch = tid;
    float sum = stats1[k * 128 + 2 * ch], sqv = stats1[k * 128 + 2 * ch + 1];
    float mean = sum * (1.f / 16384.f);
    float var  = sqv * (1.f / 16384.f) - mean * mean;
    float s = bn1g[k * 64 + ch] * rsqrtf(fmaxf(var, 0.f) + 1e-5f);
    s1s[ch] = s;
    t1s[ch] = bn1b[k * 64 + ch] - mean * s;
  } else if (tid < 160) {
    const int ch = tid - 64;
    float sum = stats2[k * 192 + 2 * ch], sqv = stats2[k * 192 + 2 * ch + 1];
    float mean = sum * (1.f / 16384.f);
    float var  = sqv * (1.f / 16384.f) - mean * mean;
    float s2 = bn2g[k * 96 + ch] * rsqrtf(fmaxf(var, 0.f) + 1e-5f);
    float t2 = bn2b[k * 96 + ch] - mean * s2;
    float w3 = c3w[k * 96 + ch];
    sw2s[ch] = s2 * w3;
    cb2s[ch] = t2 * w3;
    s42s[ch] = copysignf(0.4f, w3);
  }

  bfrag8 B1[4];
  {
    const unsigned short* w1k = w1b + k * 2048;
#pragma unroll
    for (int f = 0; f < 4; ++f)
      B1[f] = *(const bfrag8*)(w1k + (16 * f + l15) * 32 + lg * 8);
  }
  bfrag8 B2[6][2];
  {
    const unsigned short* w2k = w2p + k * 6144;
#pragma unroll
    for (int f2 = 0; f2 < 6; ++f2) {
      B2[f2][0] = *(const bfrag8*)(w2k + (16 * f2 + l15) * 64 + lg * 8);
      B2[f2][1] = *(const bfrag8*)(w2k + (16 * f2 + l15) * 64 + 32 + lg * 8);
    }
  }
  __syncthreads();
#pragma unroll
  for (int f = 0; f < 4; ++f)
    B1[f] = scale_frag(B1[f], s1s[16 * f + l15]);
#pragma unroll
  for (int f2 = 0; f2 < 6; ++f2) {
    float sc = sw2s[16 * f2 + l15];
    B2[f2][0] = scale_frag(B2[f2][0], sc);
    B2[f2][1] = scale_frag(B2[f2][1], sc);
  }

  // ---- subtile loop: st = bx, bx+64, bx+128 (<144) ----
  for (int st = bx; st < 144; st += 64) {
    const int t36 = st >> 2, sub = st & 3;
    int a = 0, rem = t36;
    while (rem >= 8 - a) { rem -= 8 - a; ++a; }
    const int b = a + rem;
    const int Pb0 = a * 32 + (sub >> 1) * 16;
    const int Qb  = b * 32 + (sub & 1) * 16;

    __syncthreads();   // previous iteration's xp/lt reads complete
    if (tid < 128) {
      int r = tid >> 3, c4 = (tid & 7) * 4;
      *(f32x4*)&xp[r][c4] = *(const f32x4*)(xik + (size_t)(Pb0 + r) * 32 + c4);
    }
    __syncthreads();

    float qv8[8];
    {
      const f32x4* src = (const f32x4*)(xik + (size_t)(Qb + l15) * 32 + lg * 8);
      f32x4 v0 = src[0], v1 = src[1];
#pragma unroll
      for (int j = 0; j < 4; ++j) { qv8[j] = v0[j]; qv8[4 + j] = v1[j]; }
    }

#pragma unroll
    for (int rp = 0; rp < 4; ++rp) {
      const int plocal = wv * 4 + rp;
      const int pglob  = Pb0 + plocal;

      const float* xpp = &xp[plocal][lg * 8];
      f32x4 p0 = *(const f32x4*)xpp;
      f32x4 p1 = *(const f32x4*)(xpp + 4);
      float pvv[8];
#pragma unroll
      for (int j = 0; j < 4; ++j) { pvv[j] = p0[j]; pvv[4 + j] = p1[j]; }
      unsigned dw[4];
#pragma unroll
      for (int wj = 0; wj < 4; ++wj) {
        float d0 = fabsf(qv8[2 * wj]     - pvv[2 * wj]);
        float d1 = fabsf(qv8[2 * wj + 1] - pvv[2 * wj + 1]);
        dw[wj] = pack2bf(d0, d1);
      }
      i32x4 dwi = {(int)dw[0], (int)dw[1], (int)dw[2], (int)dw[3]};
      bfrag8 df = __builtin_bit_cast(bfrag8, dwi);

      f32x4 acc1[4];
      __builtin_amdgcn_s_setprio(1);
#pragma unroll
      for (int f = 0; f < 4; ++f) {
        f32x4 cin = *(const f32x4*)&t1s[16 * f + 4 * lg];
        acc1[f] = __builtin_amdgcn_mfma_f32_16x16x32_bf16(B1[f], df, cin, 0, 0, 0);
      }
      __builtin_amdgcn_s_setprio(0);

      unsigned paw[8];
#pragma unroll
      for (int f = 0; f < 4; ++f) {
        float h0 = acc1[f][0], h1 = acc1[f][1], h2 = acc1[f][2], h3 = acc1[f][3];
        h0 = fmaxf(h0, 0.2f * h0); h1 = fmaxf(h1, 0.2f * h1);
        h2 = fmaxf(h2, 0.2f * h2); h3 = fmaxf(h3, 0.2f * h3);
        paw[f * 2]     = pack2bf(h0, h1);
        paw[f * 2 + 1] = pack2bf(h2, h3);
      }
      i32x4 pa0i = {(int)paw[0], (int)paw[1], (int)paw[2], (int)paw[3]};
      i32x4 pa1i = {(int)paw[4], (int)paw[5], (int)paw[6], (int)paw[7]};
      bfrag8 pa0 = __builtin_bit_cast(bfrag8, pa0i);
      bfrag8 pa1 = __builtin_bit_cast(bfrag8, pa1i);

      float lp = 0.f;
      __builtin_amdgcn_s_setprio(1);
#pragma unroll
      for (int f2 = 0; f2 < 6; ++f2) {
        f32x4 cin = *(const f32x4*)&cb2s[16 * f2 + 4 * lg];
        f32x4 acc = __builtin_amdgcn_mfma_f32_16x16x32_bf16(B2[f2][0], pa0, cin, 0, 0, 0);
        acc = __builtin_amdgcn_mfma_f32_16x16x32_bf16(B2[f2][1], pa1, acc, 0, 0, 0);
        f32x4 s4 = *(const f32x4*)&s42s[16 * f2 + 4 * lg];
#pragma unroll
        for (int r = 0; r < 4; ++r) {
          float aa = acc[r];
          float ab = fmaxf(aa, -aa);
          lp = fmaf(0.6f, aa, lp);
          lp = fmaf(s4[r], ab, lp);
        }
      }
      __builtin_amdgcn_s_setprio(0);
      lp += __shfl_xor(lp, 16);
      lp += __shfl_xor(lp, 32);
      if (lg == 0) {
        logits[(size_t)k * 65536 + (size_t)pglob * 256 + Qb + l15] = lp;
        lt[plocal][l15] = lp;
      }
    }

    __syncthreads();
    if (a != b) {   // coalesced mirror write via LDS transpose tile
      const int ql = tid >> 4, pl = tid & 15;
      logits[(size_t)k * 65536 + (size_t)(Qb + ql) * 256 + Pb0 + pl] = lt[pl][ql];
    }
  }
}

// --------- softmax + adj@xi + (mlp3-folded) GCN + BN3 stats -----------------
__global__ __launch_bounds__(256) void k_graph(
    const unsigned short* __restrict__ xib,
    const float* __restrict__ logits,
    const float* __restrict__ swb,
    const float* __restrict__ gcnw,
    float* __restrict__ hi,
    float* __restrict__ stats3) {
  const int k  = blockIdx.y;
  const int pc = blockIdx.x;   // 0..31, 8 rows each
  const int tid = threadIdx.x;
  __shared__ __align__(16) unsigned char smem[40960];
  unsigned short* xis = (unsigned short*)smem;       // 256*40 = 20480B
  float* wks  = (float*)(smem + 20480);              // 2048 floats
  float* cbuf = (float*)(smem + 28672);              // 3072 floats

  {
    const s4v* src = (const s4v*)(xib + (size_t)k * 8192 + tid * 32);
    s4v* dst = (s4v*)&xis[tid * 40];
#pragma unroll
    for (int j = 0; j < 8; ++j) dst[j] = src[j];
  }
  float* swl = cbuf;          // 1024
  float* gks = cbuf + 1024;   // 2048
#pragma unroll
  for (int j = 0; j < 4; ++j) swl[tid + j * 256] = swb[k * 1024 + tid + j * 256];
#pragma unroll
  for (int j = 0; j < 8; ++j) gks[tid + j * 256] = gcnw[(size_t)k * 2048 + tid + j * 256];
  __syncthreads();

#pragma unroll
  for (int j = 0; j < 8; ++j) {
    int e = tid + j * 256;
    int u = e >> 5, v = e & 31;
    float s = 0.f;
#pragma unroll
    for (int c = 0; c < 32; ++c) s += gks[u * 32 + c] * swl[c * 32 + v];
    wks[e] = s;
  }
  __syncthreads();

  float* es    = cbuf;          // [8][260]
  float* axs   = cbuf + 2080;   // [8][34]
  float* inv_s = cbuf + 2352;   // 8
  float* s3    = cbuf + 2360;   // 64
  if (tid < 64) s3[tid] = 0.f;

  const int row = tid >> 5;    // 0..7
  const int s   = tid & 31;
  const int pglob = pc * 8 + row;
  const float* lrow = logits + (size_t)k * 65536 + (size_t)pglob * 256;

  float m = -1e30f;
  for (int q = s; q < 256; q += 32) {
    float v = lrow[q];
    m = (q == pglob) ? m : fmaxf(m, v);
  }
#pragma unroll
  for (int mm = 1; mm < 32; mm <<= 1) m = fmaxf(m, __shfl_xor(m, mm));
  float sum = 0.f;
  for (int q = s; q < 256; q += 32) {
    float e = (q == pglob) ? 0.f : __expf(lrow[q] - m);
    es[row * 260 + q] = e;
    sum += e;
  }
#pragma unroll
  for (int mm = 1; mm < 32; mm <<= 1) sum += __shfl_xor(sum, mm);
  if (s == 0) inv_s[row] = 1.f / sum;
  __syncthreads();

  float a0 = 0.f;
  for (int q = 0; q < 256; ++q)
    a0 += es[row * 260 + q] * bf2f(xis[q * 40 + s]);
  axs[row * 34 + s] = a0 * inv_s[row];
  __syncthreads();

  float h = 0.f;
  for (int u = 0; u < 32; ++u) {
    float xu = bf2f(xis[pglob * 40 + u]);
    float au = axs[row * 34 + u];
    h += xu * wks[u * 32 + s] + au * wks[(32 + u) * 32 + s];
  }
  float v = fmaxf(h, 0.2f * h);
  hi[(size_t)k * 8192 + (size_t)pglob * 32 + s] = v;
  float vs = v, vq = v * v;
  vs += __shfl_xor(vs, 32);
  vq += __shfl_xor(vq, 32);
  if ((tid & 32) == 0) {
    atomicAdd(&s3[s * 2 + 0], vs);
    atomicAdd(&s3[s * 2 + 1], vq);
  }
  __syncthreads();
  if (tid < 64) atomicAdd(&stats3[k * 64 + tid], s3[tid]);
}

// -------------------- final: BN3 (from stats) + window add ------------------
__global__ __launch_bounds__(256) void k_final(
    const float* __restrict__ xc, const float* __restrict__ hi,
    const float* __restrict__ stats3,
    const float* __restrict__ g3, const float* __restrict__ b3,
    const int* __restrict__ inv, float* __restrict__ out) {
  const int tid = threadIdx.x;
  __shared__ float cs[512], ct[512];
#pragma unroll
  for (int j = 0; j < 2; ++j) {
    int ch = tid * 2 + j;                // 0..511
    int kk = ch >> 5, c = ch & 31;
    float sum = stats3[kk * 64 + c * 2], sqv = stats3[kk * 64 + c * 2 + 1];
    float mean = sum * (1.f / 256.f);
    float var = sqv * (1.f / 256.f) - mean * mean;
    float s = g3[kk * 32 + c] * rsqrtf(fmaxf(var, 0.f) + 1e-5f);
    cs[ch] = s;
    ct[ch] = b3[kk * 32 + c] - mean * s;
  }
  __syncthreads();

  int idx = blockIdx.x * 256 + tid;      // 2097152 float4 groups
  int c4 = idx & 7, v = idx >> 3;
  int z = v & 63, y = (v >> 6) & 63, x = v >> 12;
  int sx = (x >> 2) + (x & 3) - 1;
  int sy = (y >> 2) + (y & 3) - 1;
  int sz = (z >> 2) + (z & 3) - 1;
  f32x4 add = {0.f, 0.f, 0.f, 0.f};
  if ((unsigned)sx < 16u && (unsigned)sy < 16u && (unsigned)sz < 16u) {
    int fg = ((sx << 4) + sy) * 16 + sz;
    int pi = inv[fg];
    int kk = pi >> 8;
    f32x4 h = *(const f32x4*)&hi[(size_t)pi * 32 + c4 * 4];
    int cb = kk * 32 + c4 * 4;
#pragma unroll
    for (int j = 0; j < 4; ++j) add[j] = h[j] * cs[cb + j] + ct[cb + j];
  }
  const f32x4 a = *(const f32x4*)&xc[(size_t)idx * 4];
  *(f32x4*)&out[(size_t)idx * 4] = a + add;
}

// ----------------------------------------------------------------------------
extern "C" void kernel_launch(void* const* d_in, const int* in_sizes, int n_in,
                              void* d_out, int out_size, void* d_ws, size_t ws_size,
                              hipStream_t stream) {
  const float* xc   = (const float*)d_in[0];
  const int*   ci   = (const int*)  d_in[1];
  const float* c1w  = (const float*)d_in[2];
  const float* bn1g = (const float*)d_in[4];
  const float* bn1b = (const float*)d_in[5];
  const float* c2w  = (const float*)d_in[6];
  const float* bn2g = (const float*)d_in[8];
  const float* bn2b = (const float*)d_in[9];
  const float* c3w  = (const float*)d_in[10];
  const float* gcnw = (const float*)d_in[12];
  const float* bn3g = (const float*)d_in[13];
  const float* bn3b = (const float*)d_in[14];
  const float* mw1  = (const float*)d_in[15];
  const float* mb1  = (const float*)d_in[16];
  const float* mw2  = (const float*)d_in[17];
  const float* mb2  = (const float*)d_in[18];
  const float* mw3  = (const float*)d_in[19];
  const float* mb3  = (const float*)d_in[20];

  float* wsf = (float*)d_ws;
  float*  x      = wsf + 0;          // 131072 (dead after k_order)
  float*  xi     = wsf + 131072;     // 131072
  float*  hi     = wsf + 393216;     // 131072
  float*  swb    = wsf + 524288;     // 16384
  float*  stats1 = wsf + 557056;     // 2048
  float*  stats2 = wsf + 559104;     // 3072
  float*  stats3 = wsf + 562176;     // 1024
  float*  centb  = wsf + 563200;     // 512
  float*  logits = wsf + 567296;     // 1048576
  unsigned char* wsb = (unsigned char*)d_ws;
  int* order = (int*)(wsb + 6463488);
  unsigned short* w1b = (unsigned short*)(wsb + 6463488 + 16384);
  unsigned short* w2p = (unsigned short*)(wsb + 6463488 + 16384 + 65536);
  unsigned short* xib = (unsigned short*)(wsb + 6463488 + 16384 + 65536 + 196608);
  int* inv = (int*)(wsb + 6463488 + 16384 + 65536 + 196608 + 262144);

  k_prep <<<512, 256, 0, stream>>>(xc, x, c1w, c2w, w1b, w2p, stats1);
  k_order<<<16, 256, 0, stream>>>(ci, x, order, inv, xi, xib, centb);
  k_mlp  <<<dim3(16, 16), 256, 0, stream>>>(centb, mw1, mb1, mw2, mb2, mw3, mb3, swb);
  k_conv01<0><<<dim3(36, 16), 256, 0, stream>>>(xi, w1b, w2p, stats1, stats2, bn1g, bn1b);
  k_conv01<1><<<dim3(36, 16), 256, 0, stream>>>(xi, w1b, w2p, stats1, stats2, bn1g, bn1b);
  k_conv2<<<dim3(64, 16), 256, 0, stream>>>(xi, w1b, w2p, stats1, stats2,
                                            bn1g, bn1b, bn2g, bn2b, c3w, logits);
  k_graph<<<dim3(32, 16), 256, 0, stream>>>(xib, logits, swb, gcnw, hi, stats3);
  k_final<<<8192, 256, 0, stream>>>(xc, hi, stats3, bn3g, bn3b, inv, (float*)d_out);
}

// Round 13
// 97.500 us; speedup vs baseline: 1.0761x; 1.0761x over previous
//
#include <hip/hip_runtime.h>
#include <hip/hip_bf16.h>

// ---------------------------------------------------------------------------
// ClusterGNN fused pipeline for MI355X (gfx950).  Round 13.
//   7 dispatches: prep / order / c0mlp / conv1 / conv2 / graph / final.
//   - conv2 reverted to flat (144,16) grid (dynamic HW scheduling beats
//     static persistent assignment: r12 post-mortem).
//   - k_mlp merged into conv0's dispatch (union grid (52,16)).
//   - BN3 fused into k_final via inverse index (from r12).
// ---------------------------------------------------------------------------

typedef short bfrag8 __attribute__((ext_vector_type(8)));   // 8 bf16 (4 VGPR)
typedef float f32x4  __attribute__((ext_vector_type(4)));
typedef int   i32x4  __attribute__((ext_vector_type(4)));
typedef short s4v    __attribute__((ext_vector_type(4)));

#define DI __device__ __forceinline__

DI unsigned short f2bf(float f) {
  return __builtin_bit_cast(unsigned short, __float2bfloat16(f));
}
DI float bf2f(unsigned short u) {
  return __builtin_bit_cast(float, ((unsigned)u) << 16);
}
// pack two floats to two bf16 (round-half-up) in one u32 (lo -> low half)
DI unsigned pack2bf(float lo, float hi) {
  unsigned ulo = __builtin_bit_cast(unsigned, lo) + 0x8000u;
  unsigned uhi = __builtin_bit_cast(unsigned, hi) + 0x8000u;
  return __builtin_amdgcn_perm(uhi, ulo, 0x07060302u);
}
// scale all 8 bf16 lanes of a fragment by sc
DI bfrag8 scale_frag(bfrag8 v, float sc) {
  i32x4 wi = __builtin_bit_cast(i32x4, v);
  i32x4 o;
#pragma unroll
  for (int j = 0; j < 4; ++j) {
    unsigned u = (unsigned)wi[j];
    float lo = bf2f((unsigned short)(u & 0xffffu));
    float hi = bf2f((unsigned short)(u >> 16));
    o[j] = (int)pack2bf(lo * sc, hi * sc);
  }
  return __builtin_bit_cast(bfrag8, o);
}

// ------------------------ prep: pool + wcvt + stats zero --------------------
__global__ __launch_bounds__(256) void k_prep(
    const float* __restrict__ xc, float* __restrict__ x,
    const float* __restrict__ w1, const float* __restrict__ w2,
    unsigned short* __restrict__ w1b, unsigned short* __restrict__ w2p,
    float* __restrict__ statsz) {
  const int bid = blockIdx.x, tid = threadIdx.x;
  if (bid < 128) {
    int idx = bid * 256 + tid;      // 32768 float4s
    int c4 = idx & 7, g = idx >> 3;
    int gz = g & 15, gy = (g >> 4) & 15, gx = g >> 8;
    f32x4 s = {0.f, 0.f, 0.f, 0.f};
    for (int ix = 0; ix < 4; ++ix)
      for (int iy = 0; iy < 4; ++iy)
        for (int iz = 0; iz < 4; ++iz) {
          int X = gx * 4 + ix, Y = gy * 4 + iy, Z = gz * 4 + iz;
          s += *(const f32x4*)&xc[(size_t)(((X << 6) | Y) << 6 | Z) * 32 + c4 * 4];
        }
    *(f32x4*)&x[(size_t)idx * 4] = s * (1.f / 64.f);
    if (bid < 24) statsz[bid * 256 + tid] = 0.f;   // stats1|2|3 zero (6144)
  } else {
    int i = (bid - 128) * 256 + tid;               // 98304
    if (i < 32768) w1b[i] = f2bf(w1[i]);
    int o = i >> 6, cc = i & 63;
    int s = cc >> 5, kp = cc & 31;
    int src = 32 * s + 16 * ((kp >> 2) & 1) + 4 * (kp >> 3) + (kp & 3);
    w2p[i] = f2bf(w2[(size_t)o * 64 + src]);
  }
}

// ------------------- order + gather + centroid + inverse --------------------
__global__ __launch_bounds__(256) void k_order(
    const int* __restrict__ ci, const float* __restrict__ x,
    int* __restrict__ order, int* __restrict__ inv, float* __restrict__ xi,
    unsigned short* __restrict__ xib, float* __restrict__ centb) {
  const int k = blockIdx.x, t = threadIdx.x;
  __shared__ int scnt[256];
  __shared__ int ordl[256];
  __shared__ unsigned short xls[256 * 36];
  __shared__ float red[256];

  int match[16];
  int cnt = 0;
#pragma unroll
  for (int j = 0; j < 16; ++j) { match[j] = (ci[t * 16 + j] == k); cnt += match[j]; }
  scnt[t] = cnt;
  __syncthreads();
  for (int off = 1; off < 256; off <<= 1) {
    int v = (t >= off) ? scnt[t - off] : 0;
    __syncthreads();
    scnt[t] += v;
    __syncthreads();
  }
  int pos = scnt[t] - cnt;
#pragma unroll
  for (int j = 0; j < 16; ++j)
    if (match[j]) ordl[pos++] = t * 16 + j;
  __syncthreads();
  int src = ordl[t];
  order[k * 256 + t] = src;
  inv[src] = k * 256 + t;
  const f32x4* xr = (const f32x4*)(x + (size_t)src * 32);
  f32x4* xo = (f32x4*)(xi + ((size_t)k * 256 + t) * 32);
  uint2* xb = (uint2*)(xib + ((size_t)k * 256 + t) * 32);
  uint2* xl = (uint2*)&xls[t * 36];
#pragma unroll
  for (int c = 0; c < 8; ++c) {
    f32x4 v = xr[c];
    xo[c] = v;
    unsigned int lo = f2bf(v[0]) | ((unsigned)f2bf(v[1]) << 16);
    unsigned int hi = f2bf(v[2]) | ((unsigned)f2bf(v[3]) << 16);
    xb[c] = make_uint2(lo, hi);
    xl[c] = make_uint2(lo, hi);
  }
  __syncthreads();

  {  // centroid
    int c = t & 31, rp = t >> 5;
    float ssum = 0.f;
    for (int r = rp; r < 256; r += 8) ssum += bf2f(xls[r * 36 + c]);
    red[t] = ssum;
  }
  __syncthreads();
  if (t < 32) {
    float tot = 0.f;
#pragma unroll
    for (int g = 0; g < 8; ++g) tot += red[g * 32 + t];
    centb[k * 32 + t] = tot * (1.f / 256.f);
  }
}

// --------------- union kernel: conv0 stats pass (bx<36) | MLP (bx>=36) ------
__global__ __launch_bounds__(256, 4) void k_c0mlp(
    const float* __restrict__ xi,
    const unsigned short* __restrict__ w1b,
    float* stats1,
    const float* __restrict__ centb,
    const float* __restrict__ mw1, const float* __restrict__ mb1,
    const float* __restrict__ mw2, const float* __restrict__ mb2,
    const float* __restrict__ mw3, const float* __restrict__ mb3,
    float* __restrict__ swb) {
  const int k = blockIdx.y;
  const int tid = threadIdx.x;
  __shared__ __align__(16) float xp[32][32];
  __shared__ float sred[256];     // conv0 uses 128; mlp reuses as red
  __shared__ float cent[32];
  __shared__ float h1[128];
  __shared__ float h2s[256];

  if (blockIdx.x >= 36) {
    // ---------------- MLP path ----------------
    const int bx = blockIdx.x - 36;
    if (tid < 32) cent[tid] = centb[k * 32 + tid];
    __syncthreads();
    if (tid < 128) {
      float s = mb1[tid];
#pragma unroll
      for (int c = 0; c < 32; ++c) s += cent[c] * mw1[c * 128 + tid];
      h1[tid] = fmaxf(s, 0.f);
    }
    __syncthreads();
    {
      float s = mb2[tid];
      for (int j = 0; j < 128; ++j) s += h1[j] * mw2[j * 256 + tid];
      h2s[tid] = fmaxf(s, 0.f);
    }
    __syncthreads();
    const int o = bx * 64 + (tid & 63);
    const int part = tid >> 6;
    float s = 0.f;
    const float* m3 = mw3 + (size_t)(part * 64) * 1024 + o;
#pragma unroll 8
    for (int j = 0; j < 64; ++j) s += h2s[part * 64 + j] * m3[j * 1024];
    sred[tid] = s;
    __syncthreads();
    if (tid < 64) {
      float tot = sred[tid] + sred[tid + 64] + sred[tid + 128] + sred[tid + 192] + mb3[o];
      swb[k * 1024 + o] = 1.f / (1.f + __expf(-tot));
    }
    return;
  }

  // ---------------- conv0 stats path (sampled 1/4) ----------------
  const int t36 = blockIdx.x;
  int a = 0, rem = t36;
  while (rem >= 8 - a) { rem -= 8 - a; ++a; }
  const int b = a + rem;                 // a<=b
  const float w = (a == b) ? 1.f : 2.f;

  const int lane = tid & 63;
  const int wv  = tid >> 6;
  const int l15 = lane & 15;
  const int lg  = lane >> 4;
  const int Pb0 = a * 32, Qb = b * 32;

  const float* xik = xi + (size_t)k * 8192;
  {
    int r = tid >> 3, c4 = (tid & 7) * 4;
    *(f32x4*)&xp[r][c4] = *(const f32x4*)(xik + (size_t)(Pb0 + r) * 32 + c4);
  }
  if (tid < 128) sred[tid] = 0.f;

  float qv[2][8];
#pragma unroll
  for (int qg = 0; qg < 2; ++qg) {
    const f32x4* src = (const f32x4*)(xik + (size_t)(Qb + qg * 16 + l15) * 32 + lg * 8);
    f32x4 v0 = src[0], v1 = src[1];
#pragma unroll
    for (int j = 0; j < 4; ++j) { qv[qg][j] = v0[j]; qv[qg][4 + j] = v1[j]; }
  }

  bfrag8 B1[4];
  {
    const unsigned short* w1k = w1b + k * 2048;
#pragma unroll
    for (int f = 0; f < 4; ++f)
      B1[f] = *(const bfrag8*)(w1k + (16 * f + l15) * 32 + lg * 8);
  }

  float ss[16], sq[16];
#pragma unroll
  for (int i = 0; i < 16; ++i) { ss[i] = 0.f; sq[i] = 0.f; }

  __syncthreads();

  const f32x4 z = {0.f, 0.f, 0.f, 0.f};
  bfrag8 dfa[4];
#pragma unroll
  for (int rp = 0; rp < 4; ++rp) {
    const int pl = rp >> 1, qg = rp & 1;
    const int plocal = wv * 8 + pl * 4;
    const float* xpp = &xp[plocal][lg * 8];
    f32x4 p0 = *(const f32x4*)xpp;
    f32x4 p1 = *(const f32x4*)(xpp + 4);
    float pvv[8];
#pragma unroll
    for (int j = 0; j < 4; ++j) { pvv[j] = p0[j]; pvv[4 + j] = p1[j]; }
    unsigned dw[4];
#pragma unroll
    for (int wj = 0; wj < 4; ++wj) {
      float d0 = fabsf(qv[qg][2 * wj]     - pvv[2 * wj]);
      float d1 = fabsf(qv[qg][2 * wj + 1] - pvv[2 * wj + 1]);
      dw[wj] = pack2bf(d0, d1);
    }
    i32x4 dwi = {(int)dw[0], (int)dw[1], (int)dw[2], (int)dw[3]};
    dfa[rp] = __builtin_bit_cast(bfrag8, dwi);
  }

#pragma unroll
  for (int rp = 0; rp < 4; ++rp) {
    f32x4 acc1[4];
    __builtin_amdgcn_s_setprio(1);
#pragma unroll
    for (int f = 0; f < 4; ++f)
      acc1[f] = __builtin_amdgcn_mfma_f32_16x16x32_bf16(B1[f], dfa[rp], z, 0, 0, 0);
    __builtin_amdgcn_s_setprio(0);
#pragma unroll
    for (int f = 0; f < 4; ++f)
#pragma unroll
      for (int r = 0; r < 4; ++r) {
        float h = acc1[f][r];
        ss[f * 4 + r] += h; sq[f * 4 + r] = fmaf(h, h, sq[f * 4 + r]);
      }
  }

#pragma unroll
  for (int i = 0; i < 16; ++i) {
#pragma unroll
    for (int m = 1; m <= 8; m <<= 1) {
      ss[i] += __shfl_xor(ss[i], m);
      sq[i] += __shfl_xor(sq[i], m);
    }
  }
  if (l15 == 0) {
#pragma unroll
    for (int i = 0; i < 16; ++i) {
      int ch = 16 * (i >> 2) + 4 * lg + (i & 3);
      atomicAdd(&sred[ch * 2 + 0], ss[i] * w);
      atomicAdd(&sred[ch * 2 + 1], sq[i] * w);
    }
  }
  __syncthreads();
  if (tid < 128) atomicAdd(&stats1[k * 128 + tid], sred[tid]);
}

// ------------------- conv1: BN2 stats pass (sampled 1/4) --------------------
__global__ __launch_bounds__(256, 3) void k_conv1(
    const float* __restrict__ xi,
    const unsigned short* __restrict__ w1b,
    const unsigned short* __restrict__ w2p,
    const float* __restrict__ stats1, float* stats2,
    const float* __restrict__ bn1g, const float* __restrict__ bn1b) {
  const int k   = blockIdx.y;
  const int t36 = blockIdx.x;
  int a = 0, rem = t36;
  while (rem >= 8 - a) { rem -= 8 - a; ++a; }
  const int b = a + rem;                 // a<=b
  const float w = (a == b) ? 1.f : 2.f;

  const int tid = threadIdx.x;
  const int lane = tid & 63;
  const int wv  = tid >> 6;
  const int l15 = lane & 15;
  const int lg  = lane >> 4;
  const int Pb0 = a * 32, Qb = b * 32;

  __shared__ __align__(16) float xp[32][32];
  __shared__ float sred[192];
  __shared__ __align__(16) float s1s[64];
  __shared__ __align__(16) float t1s[64];

  const float* xik = xi + (size_t)k * 8192;
  {
    int r = tid >> 3, c4 = (tid & 7) * 4;
    *(f32x4*)&xp[r][c4] = *(const f32x4*)(xik + (size_t)(Pb0 + r) * 32 + c4);
  }
  if (tid < 192) sred[tid] = 0.f;
  if (tid >= 192) {
    const int ch = tid - 192;
    float sum = stats1[k * 128 + 2 * ch], sqv = stats1[k * 128 + 2 * ch + 1];
    float mean = sum * (1.f / 16384.f);
    float var  = sqv * (1.f / 16384.f) - mean * mean;
    float s = bn1g[k * 64 + ch] * rsqrtf(fmaxf(var, 0.f) + 1e-5f);
    s1s[ch] = s;
    t1s[ch] = bn1b[k * 64 + ch] - mean * s;
  }

  float qv[2][8];
#pragma unroll
  for (int qg = 0; qg < 2; ++qg) {
    const f32x4* src = (const f32x4*)(xik + (size_t)(Qb + qg * 16 + l15) * 32 + lg * 8);
    f32x4 v0 = src[0], v1 = src[1];
#pragma unroll
    for (int j = 0; j < 4; ++j) { qv[qg][j] = v0[j]; qv[qg][4 + j] = v1[j]; }
  }

  bfrag8 B1[4];
  {
    const unsigned short* w1k = w1b + k * 2048;
#pragma unroll
    for (int f = 0; f < 4; ++f)
      B1[f] = *(const bfrag8*)(w1k + (16 * f + l15) * 32 + lg * 8);
  }
  bfrag8 B2[6][2];
  {
    const unsigned short* w2k = w2p + k * 6144;
#pragma unroll
    for (int f2 = 0; f2 < 6; ++f2) {
      B2[f2][0] = *(const bfrag8*)(w2k + (16 * f2 + l15) * 64 + lg * 8);
      B2[f2][1] = *(const bfrag8*)(w2k + (16 * f2 + l15) * 64 + 32 + lg * 8);
    }
  }

  float ss[24], sq[24];
#pragma unroll
  for (int i = 0; i < 24; ++i) { ss[i] = 0.f; sq[i] = 0.f; }

  __syncthreads();

#pragma unroll
  for (int f = 0; f < 4; ++f)
    B1[f] = scale_frag(B1[f], s1s[16 * f + l15]);

  const f32x4 z = {0.f, 0.f, 0.f, 0.f};

  bfrag8 dfa[4];
#pragma unroll
  for (int rp = 0; rp < 4; ++rp) {
    const int pl = rp >> 1, qg = rp & 1;
    const int plocal = wv * 8 + pl * 4;
    const float* xpp = &xp[plocal][lg * 8];
    f32x4 p0 = *(const f32x4*)xpp;
    f32x4 p1 = *(const f32x4*)(xpp + 4);
    float pvv[8];
#pragma unroll
    for (int j = 0; j < 4; ++j) { pvv[j] = p0[j]; pvv[4 + j] = p1[j]; }
    unsigned dw[4];
#pragma unroll
    for (int wj = 0; wj < 4; ++wj) {
      float d0 = fabsf(qv[qg][2 * wj]     - pvv[2 * wj]);
      float d1 = fabsf(qv[qg][2 * wj + 1] - pvv[2 * wj + 1]);
      dw[wj] = pack2bf(d0, d1);
    }
    i32x4 dwi = {(int)dw[0], (int)dw[1], (int)dw[2], (int)dw[3]};
    dfa[rp] = __builtin_bit_cast(bfrag8, dwi);
  }

#pragma unroll
  for (int rp = 0; rp < 4; ++rp) {
    f32x4 acc1[4];
    __builtin_amdgcn_s_setprio(1);
#pragma unroll
    for (int f = 0; f < 4; ++f) {
      f32x4 cin = *(const f32x4*)&t1s[16 * f + 4 * lg];
      acc1[f] = __builtin_amdgcn_mfma_f32_16x16x32_bf16(B1[f], dfa[rp], cin, 0, 0, 0);
    }
    __builtin_amdgcn_s_setprio(0);

    unsigned paw[8];
#pragma unroll
    for (int f = 0; f < 4; ++f) {
      float h0 = acc1[f][0], h1 = acc1[f][1], h2 = acc1[f][2], h3 = acc1[f][3];
      h0 = fmaxf(h0, 0.2f * h0); h1 = fmaxf(h1, 0.2f * h1);
      h2 = fmaxf(h2, 0.2f * h2); h3 = fmaxf(h3, 0.2f * h3);
      paw[f * 2]     = pack2bf(h0, h1);
      paw[f * 2 + 1] = pack2bf(h2, h3);
    }
    i32x4 pa0i = {(int)paw[0], (int)paw[1], (int)paw[2], (int)paw[3]};
    i32x4 pa1i = {(int)paw[4], (int)paw[5], (int)paw[6], (int)paw[7]};
    bfrag8 pa0 = __builtin_bit_cast(bfrag8, pa0i);
    bfrag8 pa1 = __builtin_bit_cast(bfrag8, pa1i);

    __builtin_amdgcn_s_setprio(1);
#pragma unroll
    for (int f2 = 0; f2 < 6; ++f2) {
      f32x4 acc = __builtin_amdgcn_mfma_f32_16x16x32_bf16(B2[f2][0], pa0, z, 0, 0, 0);
      acc = __builtin_amdgcn_mfma_f32_16x16x32_bf16(B2[f2][1], pa1, acc, 0, 0, 0);
#pragma unroll
      for (int r = 0; r < 4; ++r) {
        float h = acc[r];
        ss[f2 * 4 + r] += h; sq[f2 * 4 + r] = fmaf(h, h, sq[f2 * 4 + r]);
      }
    }
    __builtin_amdgcn_s_setprio(0);
  }

#pragma unroll
  for (int i = 0; i < 24; ++i) {
#pragma unroll
    for (int m = 1; m <= 8; m <<= 1) {
      ss[i] += __shfl_xor(ss[i], m);
      sq[i] += __shfl_xor(sq[i], m);
    }
  }
  if (l15 == 0) {
#pragma unroll
    for (int i = 0; i < 24; ++i) {
      int ch = 16 * (i >> 2) + 4 * lg + (i & 3);
      atomicAdd(&sred[ch * 2 + 0], ss[i] * w);
      atomicAdd(&sred[ch * 2 + 1], sq[i] * w);
    }
  }
  __syncthreads();
  if (tid < 192) atomicAdd(&stats2[k * 192 + tid], sred[tid]);
}

// ------------------- logits pass (flat grid, dynamic sched) -----------------
__global__ __launch_bounds__(256, 4) void k_conv2(
    const float* __restrict__ xi,
    const unsigned short* __restrict__ w1b,
    const unsigned short* __restrict__ w2p,
    const float* __restrict__ stats1, const float* __restrict__ stats2,
    const float* __restrict__ bn1g, const float* __restrict__ bn1b,
    const float* __restrict__ bn2g, const float* __restrict__ bn2b,
    const float* __restrict__ c3w,
    float* __restrict__ logits) {
  const int k   = blockIdx.y;
  const int t36 = blockIdx.x >> 2;
  const int sub = blockIdx.x & 3;
  int a = 0, rem = t36;
  while (rem >= 8 - a) { rem -= 8 - a; ++a; }
  const int b = a + rem;
  const int Pb0 = a * 32 + (sub >> 1) * 16;
  const int Qb  = b * 32 + (sub & 1) * 16;

  const int tid = threadIdx.x;
  const int lane = tid & 63;
  const int wv  = tid >> 6;
  const int l15 = lane & 15;
  const int lg  = lane >> 4;

  __shared__ __align__(16) float xp[16][32];
  __shared__ __align__(16) float s1s[64];
  __shared__ __align__(16) float t1s[64];
  __shared__ __align__(16) float sw2s[96];
  __shared__ __align__(16) float cb2s[96];
  __shared__ __align__(16) float s42s[96];
  __shared__ float lt[16][17];

  const float* xik = xi + (size_t)k * 8192;

  if (tid < 128) {
    int r = tid >> 3, c4 = (tid & 7) * 4;
    *(f32x4*)&xp[r][c4] = *(const f32x4*)(xik + (size_t)(Pb0 + r) * 32 + c4);
  } else if (tid < 192) {
    const int ch = tid - 128;
    float sum = stats1[k * 128 + 2 * ch], sqv = stats1[k * 128 + 2 * ch + 1];
    float mean = sum * (1.f / 16384.f);
    float var  = sqv * (1.f / 16384.f) - mean * mean;
    float s = bn1g[k * 64 + ch] * rsqrtf(fmaxf(var, 0.f) + 1e-5f);
    s1s[ch] = s;
    t1s[ch] = bn1b[k * 64 + ch] - mean * s;
  }
  {
    // all threads also cover the 96 BN2 channels (tid 0..95 of upper half)
    int ch = tid - 160;
    if (ch >= 0 && ch < 96) {
      float sum = stats2[k * 192 + 2 * ch], sqv = stats2[k * 192 + 2 * ch + 1];
      float mean = sum * (1.f / 16384.f);
      float var  = sqv * (1.f / 16384.f) - mean * mean;
      float s2 = bn2g[k * 96 + ch] * rsqrtf(fmaxf(var, 0.f) + 1e-5f);
      float t2 = bn2b[k * 96 + ch] - mean * s2;
      float w3 = c3w[k * 96 + ch];
      sw2s[ch] = s2 * w3;
      cb2s[ch] = t2 * w3;
      s42s[ch] = copysignf(0.4f, w3);
    }
  }

  float qv8[8];
  {
    const f32x4* src = (const f32x4*)(xik + (size_t)(Qb + l15) * 32 + lg * 8);
    f32x4 v0 = src[0], v1 = src[1];
#pragma unroll
    for (int j = 0; j < 4; ++j) { qv8[j] = v0[j]; qv8[4 + j] = v1[j]; }
  }

  bfrag8 B1[4];
  {
    const unsigned short* w1k = w1b + k * 2048;
#pragma unroll
    for (int f = 0; f < 4; ++f)
      B1[f] = *(const bfrag8*)(w1k + (16 * f + l15) * 32 + lg * 8);
  }
  bfrag8 B2[6][2];
  {
    const unsigned short* w2k = w2p + k * 6144;
#pragma unroll
    for (int f2 = 0; f2 < 6; ++f2) {
      B2[f2][0] = *(const bfrag8*)(w2k + (16 * f2 + l15) * 64 + lg * 8);
      B2[f2][1] = *(const bfrag8*)(w2k + (16 * f2 + l15) * 64 + 32 + lg * 8);
    }
  }
  __syncthreads();
#pragma unroll
  for (int f = 0; f < 4; ++f)
    B1[f] = scale_frag(B1[f], s1s[16 * f + l15]);
#pragma unroll
  for (int f2 = 0; f2 < 6; ++f2) {
    float sc = sw2s[16 * f2 + l15];
    B2[f2][0] = scale_frag(B2[f2][0], sc);
    B2[f2][1] = scale_frag(B2[f2][1], sc);
  }

#pragma unroll
  for (int rp = 0; rp < 4; ++rp) {
    const int plocal = wv * 4 + rp;
    const int pglob  = Pb0 + plocal;

    const float* xpp = &xp[plocal][lg * 8];
    f32x4 p0 = *(const f32x4*)xpp;
    f32x4 p1 = *(const f32x4*)(xpp + 4);
    float pvv[8];
#pragma unroll
    for (int j = 0; j < 4; ++j) { pvv[j] = p0[j]; pvv[4 + j] = p1[j]; }
    unsigned dw[4];
#pragma unroll
    for (int wj = 0; wj < 4; ++wj) {
      float d0 = fabsf(qv8[2 * wj]     - pvv[2 * wj]);
      float d1 = fabsf(qv8[2 * wj + 1] - pvv[2 * wj + 1]);
      dw[wj] = pack2bf(d0, d1);
    }
    i32x4 dwi = {(int)dw[0], (int)dw[1], (int)dw[2], (int)dw[3]};
    bfrag8 df = __builtin_bit_cast(bfrag8, dwi);

    f32x4 acc1[4];
    __builtin_amdgcn_s_setprio(1);
#pragma unroll
    for (int f = 0; f < 4; ++f) {
      f32x4 cin = *(const f32x4*)&t1s[16 * f + 4 * lg];
      acc1[f] = __builtin_amdgcn_mfma_f32_16x16x32_bf16(B1[f], df, cin, 0, 0, 0);
    }
    __builtin_amdgcn_s_setprio(0);

    unsigned paw[8];
#pragma unroll
    for (int f = 0; f < 4; ++f) {
      float h0 = acc1[f][0], h1 = acc1[f][1], h2 = acc1[f][2], h3 = acc1[f][3];
      h0 = fmaxf(h0, 0.2f * h0); h1 = fmaxf(h1, 0.2f * h1);
      h2 = fmaxf(h2, 0.2f * h2); h3 = fmaxf(h3, 0.2f * h3);
      paw[f * 2]     = pack2bf(h0, h1);
      paw[f * 2 + 1] = pack2bf(h2, h3);
    }
    i32x4 pa0i = {(int)paw[0], (int)paw[1], (int)paw[2], (int)paw[3]};
    i32x4 pa1i = {(int)paw[4], (int)paw[5], (int)paw[6], (int)paw[7]};
    bfrag8 pa0 = __builtin_bit_cast(bfrag8, pa0i);
    bfrag8 pa1 = __builtin_bit_cast(bfrag8, pa1i);

    float lp = 0.f;
    __builtin_amdgcn_s_setprio(1);
#pragma unroll
    for (int f2 = 0; f2 < 6; ++f2) {
      f32x4 cin = *(const f32x4*)&cb2s[16 * f2 + 4 * lg];
      f32x4 acc = __builtin_amdgcn_mfma_f32_16x16x32_bf16(B2[f2][0], pa0, cin, 0, 0, 0);
      acc = __builtin_amdgcn_mfma_f32_16x16x32_bf16(B2[f2][1], pa1, acc, 0, 0, 0);
      f32x4 s4 = *(const f32x4*)&s42s[16 * f2 + 4 * lg];
#pragma unroll
      for (int r = 0; r < 4; ++r) {
        float aa = acc[r];
        float ab = fmaxf(aa, -aa);
        lp = fmaf(0.6f, aa, lp);
        lp = fmaf(s4[r], ab, lp);
      }
    }
    __builtin_amdgcn_s_setprio(0);
    lp += __shfl_xor(lp, 16);
    lp += __shfl_xor(lp, 32);
    if (lg == 0) {
      logits[(size_t)k * 65536 + (size_t)pglob * 256 + Qb + l15] = lp;
      lt[plocal][l15] = lp;
    }
  }

  if (a != b) {   // coalesced mirror write via LDS transpose tile
    __syncthreads();
    const int ql = tid >> 4, pl = tid & 15;
    logits[(size_t)k * 65536 + (size_t)(Qb + ql) * 256 + Pb0 + pl] = lt[pl][ql];
  }
}

// --------- softmax + adj@xi + (mlp3-folded) GCN + BN3 stats -----------------
__global__ __launch_bounds__(256) void k_graph(
    const unsigned short* __restrict__ xib,
    const float* __restrict__ logits,
    const float* __restrict__ swb,
    const float* __restrict__ gcnw,
    float* __restrict__ hi,
    float* __restrict__ stats3) {
  const int k  = blockIdx.y;
  const int pc = blockIdx.x;   // 0..31, 8 rows each
  const int tid = threadIdx.x;
  __shared__ __align__(16) unsigned char smem[40960];
  unsigned short* xis = (unsigned short*)smem;       // 256*40 = 20480B
  float* wks  = (float*)(smem + 20480);              // 2048 floats
  float* cbuf = (float*)(smem + 28672);              // 3072 floats

  {
    const s4v* src = (const s4v*)(xib + (size_t)k * 8192 + tid * 32);
    s4v* dst = (s4v*)&xis[tid * 40];
#pragma unroll
    for (int j = 0; j < 8; ++j) dst[j] = src[j];
  }
  float* swl = cbuf;          // 1024
  float* gks = cbuf + 1024;   // 2048
#pragma unroll
  for (int j = 0; j < 4; ++j) swl[tid + j * 256] = swb[k * 1024 + tid + j * 256];
#pragma unroll
  for (int j = 0; j < 8; ++j) gks[tid + j * 256] = gcnw[(size_t)k * 2048 + tid + j * 256];
  __syncthreads();

#pragma unroll
  for (int j = 0; j < 8; ++j) {
    int e = tid + j * 256;
    int u = e >> 5, v = e & 31;
    float s = 0.f;
#pragma unroll
    for (int c = 0; c < 32; ++c) s += gks[u * 32 + c] * swl[c * 32 + v];
    wks[e] = s;
  }
  __syncthreads();

  float* es    = cbuf;          // [8][260]
  float* axs   = cbuf + 2080;   // [8][34]
  float* inv_s = cbuf + 2352;   // 8
  float* s3    = cbuf + 2360;   // 64
  if (tid < 64) s3[tid] = 0.f;

  const int row = tid >> 5;    // 0..7
  const int s   = tid & 31;
  const int pglob = pc * 8 + row;
  const float* lrow = logits + (size_t)k * 65536 + (size_t)pglob * 256;

  float m = -1e30f;
  for (int q = s; q < 256; q += 32) {
    float v = lrow[q];
    m = (q == pglob) ? m : fmaxf(m, v);
  }
#pragma unroll
  for (int mm = 1; mm < 32; mm <<= 1) m = fmaxf(m, __shfl_xor(m, mm));
  float sum = 0.f;
  for (int q = s; q < 256; q += 32) {
    float e = (q == pglob) ? 0.f : __expf(lrow[q] - m);
    es[row * 260 + q] = e;
    sum += e;
  }
#pragma unroll
  for (int mm = 1; mm < 32; mm <<= 1) sum += __shfl_xor(sum, mm);
  if (s == 0) inv_s[row] = 1.f / sum;
  __syncthreads();

  float a0 = 0.f;
  for (int q = 0; q < 256; ++q)
    a0 += es[row * 260 + q] * bf2f(xis[q * 40 + s]);
  axs[row * 34 + s] = a0 * inv_s[row];
  __syncthreads();

  float h = 0.f;
  for (int u = 0; u < 32; ++u) {
    float xu = bf2f(xis[pglob * 40 + u]);
    float au = axs[row * 34 + u];
    h += xu * wks[u * 32 + s] + au * wks[(32 + u) * 32 + s];
  }
  float v = fmaxf(h, 0.2f * h);
  hi[(size_t)k * 8192 + (size_t)pglob * 32 + s] = v;
  float vs = v, vq = v * v;
  vs += __shfl_xor(vs, 32);
  vq += __shfl_xor(vq, 32);
  if ((tid & 32) == 0) {
    atomicAdd(&s3[s * 2 + 0], vs);
    atomicAdd(&s3[s * 2 + 1], vq);
  }
  __syncthreads();
  if (tid < 64) atomicAdd(&stats3[k * 64 + tid], s3[tid]);
}

// -------------------- final: BN3 (from stats) + window add ------------------
__global__ __launch_bounds__(256) void k_final(
    const float* __restrict__ xc, const float* __restrict__ hi,
    const float* __restrict__ stats3,
    const float* __restrict__ g3, const float* __restrict__ b3,
    const int* __restrict__ inv, float* __restrict__ out) {
  const int tid = threadIdx.x;
  __shared__ float cs[512], ct[512];
#pragma unroll
  for (int j = 0; j < 2; ++j) {
    int ch = tid * 2 + j;                // 0..511
    int kk = ch >> 5, c = ch & 31;
    float sum = stats3[kk * 64 + c * 2], sqv = stats3[kk * 64 + c * 2 + 1];
    float mean = sum * (1.f / 256.f);
    float var = sqv * (1.f / 256.f) - mean * mean;
    float s = g3[kk * 32 + c] * rsqrtf(fmaxf(var, 0.f) + 1e-5f);
    cs[ch] = s;
    ct[ch] = b3[kk * 32 + c] - mean * s;
  }
  __syncthreads();

  int idx = blockIdx.x * 256 + tid;      // 2097152 float4 groups
  int c4 = idx & 7, v = idx >> 3;
  int z = v & 63, y = (v >> 6) & 63, x = v >> 12;
  int sx = (x >> 2) + (x & 3) - 1;
  int sy = (y >> 2) + (y & 3) - 1;
  int sz = (z >> 2) + (z & 3) - 1;
  f32x4 add = {0.f, 0.f, 0.f, 0.f};
  if ((unsigned)sx < 16u && (unsigned)sy < 16u && (unsigned)sz < 16u) {
    int fg = ((sx << 4) + sy) * 16 + sz;
    int pi = inv[fg];
    int kk = pi >> 8;
    f32x4 h = *(const f32x4*)&hi[(size_t)pi * 32 + c4 * 4];
    int cb = kk * 32 + c4 * 4;
#pragma unroll
    for (int j = 0; j < 4; ++j) add[j] = h[j] * cs[cb + j] + ct[cb + j];
  }
  const f32x4 a = *(const f32x4*)&xc[(size_t)idx * 4];
  *(f32x4*)&out[(size_t)idx * 4] = a + add;
}

// ----------------------------------------------------------------------------
extern "C" void kernel_launch(void* const* d_in, const int* in_sizes, int n_in,
                              void* d_out, int out_size, void* d_ws, size_t ws_size,
                              hipStream_t stream) {
  const float* xc   = (const float*)d_in[0];
  const int*   ci   = (const int*)  d_in[1];
  const float* c1w  = (const float*)d_in[2];
  const float* bn1g = (const float*)d_in[4];
  const float* bn1b = (const float*)d_in[5];
  const float* c2w  = (const float*)d_in[6];
  const float* bn2g = (const float*)d_in[8];
  const float* bn2b = (const float*)d_in[9];
  const float* c3w  = (const float*)d_in[10];
  const float* gcnw = (const float*)d_in[12];
  const float* bn3g = (const float*)d_in[13];
  const float* bn3b = (const float*)d_in[14];
  const float* mw1  = (const float*)d_in[15];
  const float* mb1  = (const float*)d_in[16];
  const float* mw2  = (const float*)d_in[17];
  const float* mb2  = (const float*)d_in[18];
  const float* mw3  = (const float*)d_in[19];
  const float* mb3  = (const float*)d_in[20];

  float* wsf = (float*)d_ws;
  float*  x      = wsf + 0;          // 131072 (dead after k_order)
  float*  xi     = wsf + 131072;     // 131072
  float*  hi     = wsf + 393216;     // 131072
  float*  swb    = wsf + 524288;     // 16384
  float*  stats1 = wsf + 557056;     // 2048
  float*  stats2 = wsf + 559104;     // 3072
  float*  stats3 = wsf + 562176;     // 1024
  float*  centb  = wsf + 563200;     // 512
  float*  logits = wsf + 567296;     // 1048576
  unsigned char* wsb = (unsigned char*)d_ws;
  int* order = (int*)(wsb + 6463488);
  unsigned short* w1b = (unsigned short*)(wsb + 6463488 + 16384);
  unsigned short* w2p = (unsigned short*)(wsb + 6463488 + 16384 + 65536);
  unsigned short* xib = (unsigned short*)(wsb + 6463488 + 16384 + 65536 + 196608);
  int* inv = (int*)(wsb + 6463488 + 16384 + 65536 + 196608 + 262144);

  k_prep <<<512, 256, 0, stream>>>(xc, x, c1w, c2w, w1b, w2p, stats1);
  k_order<<<16, 256, 0, stream>>>(ci, x, order, inv, xi, xib, centb);
  k_c0mlp<<<dim3(52, 16), 256, 0, stream>>>(xi, w1b, stats1, centb,
                                            mw1, mb1, mw2, mb2, mw3, mb3, swb);
  k_conv1<<<dim3(36, 16), 256, 0, stream>>>(xi, w1b, w2p, stats1, stats2, bn1g, bn1b);
  k_conv2<<<dim3(144, 16), 256, 0, stream>>>(xi, w1b, w2p, stats1, stats2,
                                             bn1g, bn1b, bn2g, bn2b, c3w, logits);
  k_graph<<<dim3(32, 16), 256, 0, stream>>>(xib, logits, swb, gcnw, hi, stats3);
  k_final<<<8192, 256, 0, stream>>>(xc, hi, stats3, bn3g, bn3b, inv, (float*)d_out);
}

// Round 14
// 96.192 us; speedup vs baseline: 1.0908x; 1.0136x over previous
//
#include <hip/hip_runtime.h>
#include <hip/hip_bf16.h>

// ---------------------------------------------------------------------------
// ClusterGNN fused pipeline for MI355X (gfx950).  Round 14.
//   7 dispatches: prep / order / c0mlp / conv1 / conv2 / graph / final.
//   - stats sampling 1/4 -> 1/8 (N=8192): conv0/conv1 at 2 reps/wave.
//   - conv2 epilogue: 4 independent lp partials (was 48-deep fmaf chain).
//   - all else from round 13 (flat conv2 grid, c0mlp union, fused BN3-final).
// ---------------------------------------------------------------------------

typedef short bfrag8 __attribute__((ext_vector_type(8)));   // 8 bf16 (4 VGPR)
typedef float f32x4  __attribute__((ext_vector_type(4)));
typedef int   i32x4  __attribute__((ext_vector_type(4)));
typedef short s4v    __attribute__((ext_vector_type(4)));

#define DI __device__ __forceinline__

DI unsigned short f2bf(float f) {
  return __builtin_bit_cast(unsigned short, __float2bfloat16(f));
}
DI float bf2f(unsigned short u) {
  return __builtin_bit_cast(float, ((unsigned)u) << 16);
}
// pack two floats to two bf16 (round-half-up) in one u32 (lo -> low half)
DI unsigned pack2bf(float lo, float hi) {
  unsigned ulo = __builtin_bit_cast(unsigned, lo) + 0x8000u;
  unsigned uhi = __builtin_bit_cast(unsigned, hi) + 0x8000u;
  return __builtin_amdgcn_perm(uhi, ulo, 0x07060302u);
}
// scale all 8 bf16 lanes of a fragment by sc
DI bfrag8 scale_frag(bfrag8 v, float sc) {
  i32x4 wi = __builtin_bit_cast(i32x4, v);
  i32x4 o;
#pragma unroll
  for (int j = 0; j < 4; ++j) {
    unsigned u = (unsigned)wi[j];
    float lo = bf2f((unsigned short)(u & 0xffffu));
    float hi = bf2f((unsigned short)(u >> 16));
    o[j] = (int)pack2bf(lo * sc, hi * sc);
  }
  return __builtin_bit_cast(bfrag8, o);
}

constexpr float INV_NSAMP = 1.f / 8192.f;   // stats sample count

// ------------------------ prep: pool + wcvt + stats zero --------------------
__global__ __launch_bounds__(256) void k_prep(
    const float* __restrict__ xc, float* __restrict__ x,
    const float* __restrict__ w1, const float* __restrict__ w2,
    unsigned short* __restrict__ w1b, unsigned short* __restrict__ w2p,
    float* __restrict__ statsz) {
  const int bid = blockIdx.x, tid = threadIdx.x;
  if (bid < 128) {
    int idx = bid * 256 + tid;      // 32768 float4s
    int c4 = idx & 7, g = idx >> 3;
    int gz = g & 15, gy = (g >> 4) & 15, gx = g >> 8;
    f32x4 s = {0.f, 0.f, 0.f, 0.f};
    for (int ix = 0; ix < 4; ++ix)
      for (int iy = 0; iy < 4; ++iy)
        for (int iz = 0; iz < 4; ++iz) {
          int X = gx * 4 + ix, Y = gy * 4 + iy, Z = gz * 4 + iz;
          s += *(const f32x4*)&xc[(size_t)(((X << 6) | Y) << 6 | Z) * 32 + c4 * 4];
        }
    *(f32x4*)&x[(size_t)idx * 4] = s * (1.f / 64.f);
    if (bid < 24) statsz[bid * 256 + tid] = 0.f;   // stats1|2|3 zero (6144)
  } else {
    int i = (bid - 128) * 256 + tid;               // 98304
    if (i < 32768) w1b[i] = f2bf(w1[i]);
    int o = i >> 6, cc = i & 63;
    int s = cc >> 5, kp = cc & 31;
    int src = 32 * s + 16 * ((kp >> 2) & 1) + 4 * (kp >> 3) + (kp & 3);
    w2p[i] = f2bf(w2[(size_t)o * 64 + src]);
  }
}

// ------------------- order + gather + centroid + inverse --------------------
__global__ __launch_bounds__(256) void k_order(
    const int* __restrict__ ci, const float* __restrict__ x,
    int* __restrict__ order, int* __restrict__ inv, float* __restrict__ xi,
    unsigned short* __restrict__ xib, float* __restrict__ centb) {
  const int k = blockIdx.x, t = threadIdx.x;
  __shared__ int scnt[256];
  __shared__ int ordl[256];
  __shared__ unsigned short xls[256 * 36];
  __shared__ float red[256];

  int match[16];
  int cnt = 0;
#pragma unroll
  for (int j = 0; j < 16; ++j) { match[j] = (ci[t * 16 + j] == k); cnt += match[j]; }
  scnt[t] = cnt;
  __syncthreads();
  for (int off = 1; off < 256; off <<= 1) {
    int v = (t >= off) ? scnt[t - off] : 0;
    __syncthreads();
    scnt[t] += v;
    __syncthreads();
  }
  int pos = scnt[t] - cnt;
#pragma unroll
  for (int j = 0; j < 16; ++j)
    if (match[j]) ordl[pos++] = t * 16 + j;
  __syncthreads();
  int src = ordl[t];
  order[k * 256 + t] = src;
  inv[src] = k * 256 + t;
  const f32x4* xr = (const f32x4*)(x + (size_t)src * 32);
  f32x4* xo = (f32x4*)(xi + ((size_t)k * 256 + t) * 32);
  uint2* xb = (uint2*)(xib + ((size_t)k * 256 + t) * 32);
  uint2* xl = (uint2*)&xls[t * 36];
#pragma unroll
  for (int c = 0; c < 8; ++c) {
    f32x4 v = xr[c];
    xo[c] = v;
    unsigned int lo = f2bf(v[0]) | ((unsigned)f2bf(v[1]) << 16);
    unsigned int hi = f2bf(v[2]) | ((unsigned)f2bf(v[3]) << 16);
    xb[c] = make_uint2(lo, hi);
    xl[c] = make_uint2(lo, hi);
  }
  __syncthreads();

  {  // centroid
    int c = t & 31, rp = t >> 5;
    float ssum = 0.f;
    for (int r = rp; r < 256; r += 8) ssum += bf2f(xls[r * 36 + c]);
    red[t] = ssum;
  }
  __syncthreads();
  if (t < 32) {
    float tot = 0.f;
#pragma unroll
    for (int g = 0; g < 8; ++g) tot += red[g * 32 + t];
    centb[k * 32 + t] = tot * (1.f / 256.f);
  }
}

// --------------- union kernel: conv0 stats pass (bx<36) | MLP (bx>=36) ------
__global__ __launch_bounds__(256, 4) void k_c0mlp(
    const float* __restrict__ xi,
    const unsigned short* __restrict__ w1b,
    float* stats1,
    const float* __restrict__ centb,
    const float* __restrict__ mw1, const float* __restrict__ mb1,
    const float* __restrict__ mw2, const float* __restrict__ mb2,
    const float* __restrict__ mw3, const float* __restrict__ mb3,
    float* __restrict__ swb) {
  const int k = blockIdx.y;
  const int tid = threadIdx.x;
  __shared__ __align__(16) float xp[32][32];
  __shared__ float sred[256];     // conv0 uses 128; mlp reuses as red
  __shared__ float cent[32];
  __shared__ float h1[128];
  __shared__ float h2s[256];

  if (blockIdx.x >= 36) {
    // ---------------- MLP path ----------------
    const int bx = blockIdx.x - 36;
    if (tid < 32) cent[tid] = centb[k * 32 + tid];
    __syncthreads();
    if (tid < 128) {
      float s = mb1[tid];
#pragma unroll
      for (int c = 0; c < 32; ++c) s += cent[c] * mw1[c * 128 + tid];
      h1[tid] = fmaxf(s, 0.f);
    }
    __syncthreads();
    {
      float s = mb2[tid];
      for (int j = 0; j < 128; ++j) s += h1[j] * mw2[j * 256 + tid];
      h2s[tid] = fmaxf(s, 0.f);
    }
    __syncthreads();
    const int o = bx * 64 + (tid & 63);
    const int part = tid >> 6;
    float s = 0.f;
    const float* m3 = mw3 + (size_t)(part * 64) * 1024 + o;
#pragma unroll 8
    for (int j = 0; j < 64; ++j) s += h2s[part * 64 + j] * m3[j * 1024];
    sred[tid] = s;
    __syncthreads();
    if (tid < 64) {
      float tot = sred[tid] + sred[tid + 64] + sred[tid + 128] + sred[tid + 192] + mb3[o];
      swb[k * 1024 + o] = 1.f / (1.f + __expf(-tot));
    }
    return;
  }

  // ---------------- conv0 stats path (sampled 1/8) ----------------
  const int t36 = blockIdx.x;
  int a = 0, rem = t36;
  while (rem >= 8 - a) { rem -= 8 - a; ++a; }
  const int b = a + rem;                 // a<=b
  const float w = (a == b) ? 1.f : 2.f;

  const int lane = tid & 63;
  const int wv  = tid >> 6;
  const int l15 = lane & 15;
  const int lg  = lane >> 4;
  const int Pb0 = a * 32, Qb = b * 32;

  const float* xik = xi + (size_t)k * 8192;
  {
    int r = tid >> 3, c4 = (tid & 7) * 4;
    *(f32x4*)&xp[r][c4] = *(const f32x4*)(xik + (size_t)(Pb0 + r) * 32 + c4);
  }
  if (tid < 128) sred[tid] = 0.f;

  float qv[2][8];
#pragma unroll
  for (int qg = 0; qg < 2; ++qg) {
    const f32x4* src = (const f32x4*)(xik + (size_t)(Qb + qg * 16 + l15) * 32 + lg * 8);
    f32x4 v0 = src[0], v1 = src[1];
#pragma unroll
    for (int j = 0; j < 4; ++j) { qv[qg][j] = v0[j]; qv[qg][4 + j] = v1[j]; }
  }

  bfrag8 B1[4];
  {
    const unsigned short* w1k = w1b + k * 2048;
#pragma unroll
    for (int f = 0; f < 4; ++f)
      B1[f] = *(const bfrag8*)(w1k + (16 * f + l15) * 32 + lg * 8);
  }

  float ss[16], sq[16];
#pragma unroll
  for (int i = 0; i < 16; ++i) { ss[i] = 0.f; sq[i] = 0.f; }

  __syncthreads();

  const f32x4 z = {0.f, 0.f, 0.f, 0.f};
  bfrag8 dfa[2];
#pragma unroll
  for (int rp = 0; rp < 2; ++rp) {
    const int qg = rp;                   // one p (wv*8), both q halves
    const int plocal = wv * 8;
    const float* xpp = &xp[plocal][lg * 8];
    f32x4 p0 = *(const f32x4*)xpp;
    f32x4 p1 = *(const f32x4*)(xpp + 4);
    float pvv[8];
#pragma unroll
    for (int j = 0; j < 4; ++j) { pvv[j] = p0[j]; pvv[4 + j] = p1[j]; }
    unsigned dw[4];
#pragma unroll
    for (int wj = 0; wj < 4; ++wj) {
      float d0 = fabsf(qv[qg][2 * wj]     - pvv[2 * wj]);
      float d1 = fabsf(qv[qg][2 * wj + 1] - pvv[2 * wj + 1]);
      dw[wj] = pack2bf(d0, d1);
    }
    i32x4 dwi = {(int)dw[0], (int)dw[1], (int)dw[2], (int)dw[3]};
    dfa[rp] = __builtin_bit_cast(bfrag8, dwi);
  }

#pragma unroll
  for (int rp = 0; rp < 2; ++rp) {
    f32x4 acc1[4];
    __builtin_amdgcn_s_setprio(1);
#pragma unroll
    for (int f = 0; f < 4; ++f)
      acc1[f] = __builtin_amdgcn_mfma_f32_16x16x32_bf16(B1[f], dfa[rp], z, 0, 0, 0);
    __builtin_amdgcn_s_setprio(0);
#pragma unroll
    for (int f = 0; f < 4; ++f)
#pragma unroll
      for (int r = 0; r < 4; ++r) {
        float h = acc1[f][r];
        ss[f * 4 + r] += h; sq[f * 4 + r] = fmaf(h, h, sq[f * 4 + r]);
      }
  }

#pragma unroll
  for (int i = 0; i < 16; ++i) {
#pragma unroll
    for (int m = 1; m <= 8; m <<= 1) {
      ss[i] += __shfl_xor(ss[i], m);
      sq[i] += __shfl_xor(sq[i], m);
    }
  }
  if (l15 == 0) {
#pragma unroll
    for (int i = 0; i < 16; ++i) {
      int ch = 16 * (i >> 2) + 4 * lg + (i & 3);
      atomicAdd(&sred[ch * 2 + 0], ss[i] * w);
      atomicAdd(&sred[ch * 2 + 1], sq[i] * w);
    }
  }
  __syncthreads();
  if (tid < 128) atomicAdd(&stats1[k * 128 + tid], sred[tid]);
}

// ------------------- conv1: BN2 stats pass (sampled 1/8) --------------------
__global__ __launch_bounds__(256, 3) void k_conv1(
    const float* __restrict__ xi,
    const unsigned short* __restrict__ w1b,
    const unsigned short* __restrict__ w2p,
    const float* __restrict__ stats1, float* stats2,
    const float* __restrict__ bn1g, const float* __restrict__ bn1b) {
  const int k   = blockIdx.y;
  const int t36 = blockIdx.x;
  int a = 0, rem = t36;
  while (rem >= 8 - a) { rem -= 8 - a; ++a; }
  const int b = a + rem;                 // a<=b
  const float w = (a == b) ? 1.f : 2.f;

  const int tid = threadIdx.x;
  const int lane = tid & 63;
  const int wv  = tid >> 6;
  const int l15 = lane & 15;
  const int lg  = lane >> 4;
  const int Pb0 = a * 32, Qb = b * 32;

  __shared__ __align__(16) float xp[32][32];
  __shared__ float sred[192];
  __shared__ __align__(16) float s1s[64];
  __shared__ __align__(16) float t1s[64];

  const float* xik = xi + (size_t)k * 8192;
  {
    int r = tid >> 3, c4 = (tid & 7) * 4;
    *(f32x4*)&xp[r][c4] = *(const f32x4*)(xik + (size_t)(Pb0 + r) * 32 + c4);
  }
  if (tid < 192) sred[tid] = 0.f;
  if (tid >= 192) {
    const int ch = tid - 192;
    float sum = stats1[k * 128 + 2 * ch], sqv = stats1[k * 128 + 2 * ch + 1];
    float mean = sum * INV_NSAMP;
    float var  = sqv * INV_NSAMP - mean * mean;
    float s = bn1g[k * 64 + ch] * rsqrtf(fmaxf(var, 0.f) + 1e-5f);
    s1s[ch] = s;
    t1s[ch] = bn1b[k * 64 + ch] - mean * s;
  }

  float qv[2][8];
#pragma unroll
  for (int qg = 0; qg < 2; ++qg) {
    const f32x4* src = (const f32x4*)(xik + (size_t)(Qb + qg * 16 + l15) * 32 + lg * 8);
    f32x4 v0 = src[0], v1 = src[1];
#pragma unroll
    for (int j = 0; j < 4; ++j) { qv[qg][j] = v0[j]; qv[qg][4 + j] = v1[j]; }
  }

  bfrag8 B1[4];
  {
    const unsigned short* w1k = w1b + k * 2048;
#pragma unroll
    for (int f = 0; f < 4; ++f)
      B1[f] = *(const bfrag8*)(w1k + (16 * f + l15) * 32 + lg * 8);
  }
  bfrag8 B2[6][2];
  {
    const unsigned short* w2k = w2p + k * 6144;
#pragma unroll
    for (int f2 = 0; f2 < 6; ++f2) {
      B2[f2][0] = *(const bfrag8*)(w2k + (16 * f2 + l15) * 64 + lg * 8);
      B2[f2][1] = *(const bfrag8*)(w2k + (16 * f2 + l15) * 64 + 32 + lg * 8);
    }
  }

  float ss[24], sq[24];
#pragma unroll
  for (int i = 0; i < 24; ++i) { ss[i] = 0.f; sq[i] = 0.f; }

  __syncthreads();

#pragma unroll
  for (int f = 0; f < 4; ++f)
    B1[f] = scale_frag(B1[f], s1s[16 * f + l15]);

  const f32x4 z = {0.f, 0.f, 0.f, 0.f};

  bfrag8 dfa[2];
#pragma unroll
  for (int rp = 0; rp < 2; ++rp) {
    const int qg = rp;
    const int plocal = wv * 8;
    const float* xpp = &xp[plocal][lg * 8];
    f32x4 p0 = *(const f32x4*)xpp;
    f32x4 p1 = *(const f32x4*)(xpp + 4);
    float pvv[8];
#pragma unroll
    for (int j = 0; j < 4; ++j) { pvv[j] = p0[j]; pvv[4 + j] = p1[j]; }
    unsigned dw[4];
#pragma unroll
    for (int wj = 0; wj < 4; ++wj) {
      float d0 = fabsf(qv[qg][2 * wj]     - pvv[2 * wj]);
      float d1 = fabsf(qv[qg][2 * wj + 1] - pvv[2 * wj + 1]);
      dw[wj] = pack2bf(d0, d1);
    }
    i32x4 dwi = {(int)dw[0], (int)dw[1], (int)dw[2], (int)dw[3]};
    dfa[rp] = __builtin_bit_cast(bfrag8, dwi);
  }

#pragma unroll
  for (int rp = 0; rp < 2; ++rp) {
    f32x4 acc1[4];
    __builtin_amdgcn_s_setprio(1);
#pragma unroll
    for (int f = 0; f < 4; ++f) {
      f32x4 cin = *(const f32x4*)&t1s[16 * f + 4 * lg];
      acc1[f] = __builtin_amdgcn_mfma_f32_16x16x32_bf16(B1[f], dfa[rp], cin, 0, 0, 0);
    }
    __builtin_amdgcn_s_setprio(0);

    unsigned paw[8];
#pragma unroll
    for (int f = 0; f < 4; ++f) {
      float h0 = acc1[f][0], h1 = acc1[f][1], h2 = acc1[f][2], h3 = acc1[f][3];
      h0 = fmaxf(h0, 0.2f * h0); h1 = fmaxf(h1, 0.2f * h1);
      h2 = fmaxf(h2, 0.2f * h2); h3 = fmaxf(h3, 0.2f * h3);
      paw[f * 2]     = pack2bf(h0, h1);
      paw[f * 2 + 1] = pack2bf(h2, h3);
    }
    i32x4 pa0i = {(int)paw[0], (int)paw[1], (int)paw[2], (int)paw[3]};
    i32x4 pa1i = {(int)paw[4], (int)paw[5], (int)paw[6], (int)paw[7]};
    bfrag8 pa0 = __builtin_bit_cast(bfrag8, pa0i);
    bfrag8 pa1 = __builtin_bit_cast(bfrag8, pa1i);

    __builtin_amdgcn_s_setprio(1);
#pragma unroll
    for (int f2 = 0; f2 < 6; ++f2) {
      f32x4 acc = __builtin_amdgcn_mfma_f32_16x16x32_bf16(B2[f2][0], pa0, z, 0, 0, 0);
      acc = __builtin_amdgcn_mfma_f32_16x16x32_bf16(B2[f2][1], pa1, acc, 0, 0, 0);
#pragma unroll
      for (int r = 0; r < 4; ++r) {
        float h = acc[r];
        ss[f2 * 4 + r] += h; sq[f2 * 4 + r] = fmaf(h, h, sq[f2 * 4 + r]);
      }
    }
    __builtin_amdgcn_s_setprio(0);
  }

#pragma unroll
  for (int i = 0; i < 24; ++i) {
#pragma unroll
    for (int m = 1; m <= 8; m <<= 1) {
      ss[i] += __shfl_xor(ss[i], m);
      sq[i] += __shfl_xor(sq[i], m);
    }
  }
  if (l15 == 0) {
#pragma unroll
    for (int i = 0; i < 24; ++i) {
      int ch = 16 * (i >> 2) + 4 * lg + (i & 3);
      atomicAdd(&sred[ch * 2 + 0], ss[i] * w);
      atomicAdd(&sred[ch * 2 + 1], sq[i] * w);
    }
  }
  __syncthreads();
  if (tid < 192) atomicAdd(&stats2[k * 192 + tid], sred[tid]);
}

// ------------------- logits pass (flat grid, dynamic sched) -----------------
__global__ __launch_bounds__(256, 4) void k_conv2(
    const float* __restrict__ xi,
    const unsigned short* __restrict__ w1b,
    const unsigned short* __restrict__ w2p,
    const float* __restrict__ stats1, const float* __restrict__ stats2,
    const float* __restrict__ bn1g, const float* __restrict__ bn1b,
    const float* __restrict__ bn2g, const float* __restrict__ bn2b,
    const float* __restrict__ c3w,
    float* __restrict__ logits) {
  const int k   = blockIdx.y;
  const int t36 = blockIdx.x >> 2;
  const int sub = blockIdx.x & 3;
  int a = 0, rem = t36;
  while (rem >= 8 - a) { rem -= 8 - a; ++a; }
  const int b = a + rem;
  const int Pb0 = a * 32 + (sub >> 1) * 16;
  const int Qb  = b * 32 + (sub & 1) * 16;

  const int tid = threadIdx.x;
  const int lane = tid & 63;
  const int wv  = tid >> 6;
  const int l15 = lane & 15;
  const int lg  = lane >> 4;

  __shared__ __align__(16) float xp[16][32];
  __shared__ __align__(16) float s1s[64];
  __shared__ __align__(16) float t1s[64];
  __shared__ __align__(16) float sw2s[96];
  __shared__ __align__(16) float cb2s[96];
  __shared__ __align__(16) float s42s[96];
  __shared__ float lt[16][17];

  const float* xik = xi + (size_t)k * 8192;

  if (tid < 128) {
    int r = tid >> 3, c4 = (tid & 7) * 4;
    *(f32x4*)&xp[r][c4] = *(const f32x4*)(xik + (size_t)(Pb0 + r) * 32 + c4);
  } else if (tid < 192) {
    const int ch = tid - 128;
    float sum = stats1[k * 128 + 2 * ch], sqv = stats1[k * 128 + 2 * ch + 1];
    float mean = sum * INV_NSAMP;
    float var  = sqv * INV_NSAMP - mean * mean;
    float s = bn1g[k * 64 + ch] * rsqrtf(fmaxf(var, 0.f) + 1e-5f);
    s1s[ch] = s;
    t1s[ch] = bn1b[k * 64 + ch] - mean * s;
  }
  {
    int ch = tid - 160;
    if (ch >= 0 && ch < 96) {
      float sum = stats2[k * 192 + 2 * ch], sqv = stats2[k * 192 + 2 * ch + 1];
      float mean = sum * INV_NSAMP;
      float var  = sqv * INV_NSAMP - mean * mean;
      float s2 = bn2g[k * 96 + ch] * rsqrtf(fmaxf(var, 0.f) + 1e-5f);
      float t2 = bn2b[k * 96 + ch] - mean * s2;
      float w3 = c3w[k * 96 + ch];
      sw2s[ch] = s2 * w3;
      cb2s[ch] = t2 * w3;
      s42s[ch] = copysignf(0.4f, w3);
    }
  }

  float qv8[8];
  {
    const f32x4* src = (const f32x4*)(xik + (size_t)(Qb + l15) * 32 + lg * 8);
    f32x4 v0 = src[0], v1 = src[1];
#pragma unroll
    for (int j = 0; j < 4; ++j) { qv8[j] = v0[j]; qv8[4 + j] = v1[j]; }
  }

  bfrag8 B1[4];
  {
    const unsigned short* w1k = w1b + k * 2048;
#pragma unroll
    for (int f = 0; f < 4; ++f)
      B1[f] = *(const bfrag8*)(w1k + (16 * f + l15) * 32 + lg * 8);
  }
  bfrag8 B2[6][2];
  {
    const unsigned short* w2k = w2p + k * 6144;
#pragma unroll
    for (int f2 = 0; f2 < 6; ++f2) {
      B2[f2][0] = *(const bfrag8*)(w2k + (16 * f2 + l15) * 64 + lg * 8);
      B2[f2][1] = *(const bfrag8*)(w2k + (16 * f2 + l15) * 64 + 32 + lg * 8);
    }
  }
  __syncthreads();
#pragma unroll
  for (int f = 0; f < 4; ++f)
    B1[f] = scale_frag(B1[f], s1s[16 * f + l15]);
#pragma unroll
  for (int f2 = 0; f2 < 6; ++f2) {
    float sc = sw2s[16 * f2 + l15];
    B2[f2][0] = scale_frag(B2[f2][0], sc);
    B2[f2][1] = scale_frag(B2[f2][1], sc);
  }

#pragma unroll
  for (int rp = 0; rp < 4; ++rp) {
    const int plocal = wv * 4 + rp;
    const int pglob  = Pb0 + plocal;

    const float* xpp = &xp[plocal][lg * 8];
    f32x4 p0 = *(const f32x4*)xpp;
    f32x4 p1 = *(const f32x4*)(xpp + 4);
    float pvv[8];
#pragma unroll
    for (int j = 0; j < 4; ++j) { pvv[j] = p0[j]; pvv[4 + j] = p1[j]; }
    unsigned dw[4];
#pragma unroll
    for (int wj = 0; wj < 4; ++wj) {
      float d0 = fabsf(qv8[2 * wj]     - pvv[2 * wj]);
      float d1 = fabsf(qv8[2 * wj + 1] - pvv[2 * wj + 1]);
      dw[wj] = pack2bf(d0, d1);
    }
    i32x4 dwi = {(int)dw[0], (int)dw[1], (int)dw[2], (int)dw[3]};
    bfrag8 df = __builtin_bit_cast(bfrag8, dwi);

    f32x4 acc1[4];
    __builtin_amdgcn_s_setprio(1);
#pragma unroll
    for (int f = 0; f < 4; ++f) {
      f32x4 cin = *(const f32x4*)&t1s[16 * f + 4 * lg];
      acc1[f] = __builtin_amdgcn_mfma_f32_16x16x32_bf16(B1[f], df, cin, 0, 0, 0);
    }
    __builtin_amdgcn_s_setprio(0);

    unsigned paw[8];
#pragma unroll
    for (int f = 0; f < 4; ++f) {
      float h0 = acc1[f][0], h1 = acc1[f][1], h2 = acc1[f][2], h3 = acc1[f][3];
      h0 = fmaxf(h0, 0.2f * h0); h1 = fmaxf(h1, 0.2f * h1);
      h2 = fmaxf(h2, 0.2f * h2); h3 = fmaxf(h3, 0.2f * h3);
      paw[f * 2]     = pack2bf(h0, h1);
      paw[f * 2 + 1] = pack2bf(h2, h3);
    }
    i32x4 pa0i = {(int)paw[0], (int)paw[1], (int)paw[2], (int)paw[3]};
    i32x4 pa1i = {(int)paw[4], (int)paw[5], (int)paw[6], (int)paw[7]};
    bfrag8 pa0 = __builtin_bit_cast(bfrag8, pa0i);
    bfrag8 pa1 = __builtin_bit_cast(bfrag8, pa1i);

    // 4 independent epilogue partials (one per accumulator row r)
    float lpr[4] = {0.f, 0.f, 0.f, 0.f};
    __builtin_amdgcn_s_setprio(1);
#pragma unroll
    for (int f2 = 0; f2 < 6; ++f2) {
      f32x4 cin = *(const f32x4*)&cb2s[16 * f2 + 4 * lg];
      f32x4 acc = __builtin_amdgcn_mfma_f32_16x16x32_bf16(B2[f2][0], pa0, cin, 0, 0, 0);
      acc = __builtin_amdgcn_mfma_f32_16x16x32_bf16(B2[f2][1], pa1, acc, 0, 0, 0);
      f32x4 s4 = *(const f32x4*)&s42s[16 * f2 + 4 * lg];
#pragma unroll
      for (int r = 0; r < 4; ++r) {
        float aa = acc[r];
        float ab = fmaxf(aa, -aa);
        lpr[r] = fmaf(0.6f, aa, lpr[r]);
        lpr[r] = fmaf(s4[r], ab, lpr[r]);
      }
    }
    __builtin_amdgcn_s_setprio(0);
    float lp = (lpr[0] + lpr[1]) + (lpr[2] + lpr[3]);
    lp += __shfl_xor(lp, 16);
    lp += __shfl_xor(lp, 32);
    if (lg == 0) {
      logits[(size_t)k * 65536 + (size_t)pglob * 256 + Qb + l15] = lp;
      lt[plocal][l15] = lp;
    }
  }

  if (a != b) {   // coalesced mirror write via LDS transpose tile
    __syncthreads();
    const int ql = tid >> 4, pl = tid & 15;
    logits[(size_t)k * 65536 + (size_t)(Qb + ql) * 256 + Pb0 + pl] = lt[pl][ql];
  }
}

// --------- softmax + adj@xi + (mlp3-folded) GCN + BN3 stats -----------------
__global__ __launch_bounds__(256) void k_graph(
    const unsigned short* __restrict__ xib,
    const float* __restrict__ logits,
    const float* __restrict__ swb,
    const float* __restrict__ gcnw,
    float* __restrict__ hi,
    float* __restrict__ stats3) {
  const int k  = blockIdx.y;
  const int pc = blockIdx.x;   // 0..31, 8 rows each
  const int tid = threadIdx.x;
  __shared__ __align__(16) unsigned char smem[40960];
  unsigned short* xis = (unsigned short*)smem;       // 256*40 = 20480B
  float* wks  = (float*)(smem + 20480);              // 2048 floats
  float* cbuf = (float*)(smem + 28672);              // 3072 floats

  {
    const s4v* src = (const s4v*)(xib + (size_t)k * 8192 + tid * 32);
    s4v* dst = (s4v*)&xis[tid * 40];
#pragma unroll
    for (int j = 0; j < 8; ++j) dst[j] = src[j];
  }
  float* swl = cbuf;          // 1024
  float* gks = cbuf + 1024;   // 2048
#pragma unroll
  for (int j = 0; j < 4; ++j) swl[tid + j * 256] = swb[k * 1024 + tid + j * 256];
#pragma unroll
  for (int j = 0; j < 8; ++j) gks[tid + j * 256] = gcnw[(size_t)k * 2048 + tid + j * 256];
  __syncthreads();

#pragma unroll
  for (int j = 0; j < 8; ++j) {
    int e = tid + j * 256;
    int u = e >> 5, v = e & 31;
    float s = 0.f;
#pragma unroll
    for (int c = 0; c < 32; ++c) s += gks[u * 32 + c] * swl[c * 32 + v];
    wks[e] = s;
  }
  __syncthreads();

  float* es    = cbuf;          // [8][260]
  float* axs   = cbuf + 2080;   // [8][34]
  float* inv_s = cbuf + 2352;   // 8
  float* s3    = cbuf + 2360;   // 64
  if (tid < 64) s3[tid] = 0.f;

  const int row = tid >> 5;    // 0..7
  const int s   = tid & 31;
  const int pglob = pc * 8 + row;
  const float* lrow = logits + (size_t)k * 65536 + (size_t)pglob * 256;

  float m = -1e30f;
  for (int q = s; q < 256; q += 32) {
    float v = lrow[q];
    m = (q == pglob) ? m : fmaxf(m, v);
  }
#pragma unroll
  for (int mm = 1; mm < 32; mm <<= 1) m = fmaxf(m, __shfl_xor(m, mm));
  float sum = 0.f;
  for (int q = s; q < 256; q += 32) {
    float e = (q == pglob) ? 0.f : __expf(lrow[q] - m);
    es[row * 260 + q] = e;
    sum += e;
  }
#pragma unroll
  for (int mm = 1; mm < 32; mm <<= 1) sum += __shfl_xor(sum, mm);
  if (s == 0) inv_s[row] = 1.f / sum;
  __syncthreads();

  float a0 = 0.f;
  for (int q = 0; q < 256; ++q)
    a0 += es[row * 260 + q] * bf2f(xis[q * 40 + s]);
  axs[row * 34 + s] = a0 * inv_s[row];
  __syncthreads();

  float h = 0.f;
  for (int u = 0; u < 32; ++u) {
    float xu = bf2f(xis[pglob * 40 + u]);
    float au = axs[row * 34 + u];
    h += xu * wks[u * 32 + s] + au * wks[(32 + u) * 32 + s];
  }
  float v = fmaxf(h, 0.2f * h);
  hi[(size_t)k * 8192 + (size_t)pglob * 32 + s] = v;
  float vs = v, vq = v * v;
  vs += __shfl_xor(vs, 32);
  vq += __shfl_xor(vq, 32);
  if ((tid & 32) == 0) {
    atomicAdd(&s3[s * 2 + 0], vs);
    atomicAdd(&s3[s * 2 + 1], vq);
  }
  __syncthreads();
  if (tid < 64) atomicAdd(&stats3[k * 64 + tid], s3[tid]);
}

// -------------------- final: BN3 (from stats) + window add ------------------
__global__ __launch_bounds__(256) void k_final(
    const float* __restrict__ xc, const float* __restrict__ hi,
    const float* __restrict__ stats3,
    const float* __restrict__ g3, const float* __restrict__ b3,
    const int* __restrict__ inv, float* __restrict__ out) {
  const int tid = threadIdx.x;
  __shared__ float cs[512], ct[512];
#pragma unroll
  for (int j = 0; j < 2; ++j) {
    int ch = tid * 2 + j;                // 0..511
    int kk = ch >> 5, c = ch & 31;
    float sum = stats3[kk * 64 + c * 2], sqv = stats3[kk * 64 + c * 2 + 1];
    float mean = sum * (1.f / 256.f);
    float var = sqv * (1.f / 256.f) - mean * mean;
    float s = g3[kk * 32 + c] * rsqrtf(fmaxf(var, 0.f) + 1e-5f);
    cs[ch] = s;
    ct[ch] = b3[kk * 32 + c] - mean * s;
  }
  __syncthreads();

  int idx = blockIdx.x * 256 + tid;      // 2097152 float4 groups
  int c4 = idx & 7, v = idx >> 3;
  int z = v & 63, y = (v >> 6) & 63, x = v >> 12;
  int sx = (x >> 2) + (x & 3) - 1;
  int sy = (y >> 2) + (y & 3) - 1;
  int sz = (z >> 2) + (z & 3) - 1;
  f32x4 add = {0.f, 0.f, 0.f, 0.f};
  if ((unsigned)sx < 16u && (unsigned)sy < 16u && (unsigned)sz < 16u) {
    int fg = ((sx << 4) + sy) * 16 + sz;
    int pi = inv[fg];
    int kk = pi >> 8;
    f32x4 h = *(const f32x4*)&hi[(size_t)pi * 32 + c4 * 4];
    int cb = kk * 32 + c4 * 4;
#pragma unroll
    for (int j = 0; j < 4; ++j) add[j] = h[j] * cs[cb + j] + ct[cb + j];
  }
  const f32x4 a = *(const f32x4*)&xc[(size_t)idx * 4];
  *(f32x4*)&out[(size_t)idx * 4] = a + add;
}

// ----------------------------------------------------------------------------
extern "C" void kernel_launch(void* const* d_in, const int* in_sizes, int n_in,
                              void* d_out, int out_size, void* d_ws, size_t ws_size,
                              hipStream_t stream) {
  const float* xc   = (const float*)d_in[0];
  const int*   ci   = (const int*)  d_in[1];
  const float* c1w  = (const float*)d_in[2];
  const float* bn1g = (const float*)d_in[4];
  const float* bn1b = (const float*)d_in[5];
  const float* c2w  = (const float*)d_in[6];
  const float* bn2g = (const float*)d_in[8];
  const float* bn2b = (const float*)d_in[9];
  const float* c3w  = (const float*)d_in[10];
  const float* gcnw = (const float*)d_in[12];
  const float* bn3g = (const float*)d_in[13];
  const float* bn3b = (const float*)d_in[14];
  const float* mw1  = (const float*)d_in[15];
  const float* mb1  = (const float*)d_in[16];
  const float* mw2  = (const float*)d_in[17];
  const float* mb2  = (const float*)d_in[18];
  const float* mw3  = (const float*)d_in[19];
  const float* mb3  = (const float*)d_in[20];

  float* wsf = (float*)d_ws;
  float*  x      = wsf + 0;          // 131072 (dead after k_order)
  float*  xi     = wsf + 131072;     // 131072
  float*  hi     = wsf + 393216;     // 131072
  float*  swb    = wsf + 524288;     // 16384
  float*  stats1 = wsf + 557056;     // 2048
  float*  stats2 = wsf + 559104;     // 3072
  float*  stats3 = wsf + 562176;     // 1024
  float*  centb  = wsf + 563200;     // 512
  float*  logits = wsf + 567296;     // 1048576
  unsigned char* wsb = (unsigned char*)d_ws;
  int* order = (int*)(wsb + 6463488);
  unsigned short* w1b = (unsigned short*)(wsb + 6463488 + 16384);
  unsigned short* w2p = (unsigned short*)(wsb + 6463488 + 16384 + 65536);
  unsigned short* xib = (unsigned short*)(wsb + 6463488 + 16384 + 65536 + 196608);
  int* inv = (int*)(wsb + 6463488 + 16384 + 65536 + 196608 + 262144);

  k_prep <<<512, 256, 0, stream>>>(xc, x, c1w, c2w, w1b, w2p, stats1);
  k_order<<<16, 256, 0, stream>>>(ci, x, order, inv, xi, xib, centb);
  k_c0mlp<<<dim3(52, 16), 256, 0, stream>>>(xi, w1b, stats1, centb,
                                            mw1, mb1, mw2, mb2, mw3, mb3, swb);
  k_conv1<<<dim3(36, 16), 256, 0, stream>>>(xi, w1b, w2p, stats1, stats2, bn1g, bn1b);
  k_conv2<<<dim3(144, 16), 256, 0, stream>>>(xi, w1b, w2p, stats1, stats2,
                                             bn1g, bn1b, bn2g, bn2b, c3w, logits);
  k_graph<<<dim3(32, 16), 256, 0, stream>>>(xib, logits, swb, gcnw, hi, stats3);
  k_final<<<8192, 256, 0, stream>>>(xc, hi, stats3, bn3g, bn3b, inv, (float*)d_out);
}